// Round 10
// baseline (554.959 us; speedup 1.0000x reference)
//
#include <hip/hip_runtime.h>

#define Nn 20000
#define Ee 240000
#define ET (Ee + Nn)        // 260000 edges incl self-loops
#define EMB 256
#define HE  512             // H * EMB
#define NG  128             // graphs
#define DENSE 512
#define NCLS 10
#define SLOPE 0.2f
#define NB 79               // ceil(Nn/256) scan blocks

typedef unsigned short u16;
typedef short bf16x8 __attribute__((ext_vector_type(8)));
typedef float f32x4 __attribute__((ext_vector_type(4)));

__device__ __forceinline__ u16 f2bf(float f) {
    unsigned u = __float_as_uint(f);
    unsigned r = (u + 0x7fffu + ((u >> 16) & 1u)) >> 16;
    return (u16)r;
}
__device__ __forceinline__ float bf2f(u16 u) {
    return __uint_as_float(((unsigned)u) << 16);
}

// ---------------- reduction helpers ----------------
__device__ __forceinline__ float wave_sum(float v) {
#pragma unroll
    for (int off = 32; off > 0; off >>= 1) v += __shfl_down(v, off, 64);
    return v;
}
__device__ __forceinline__ float block_sum4(float v, volatile float* red4) {
    v = wave_sum(v);
    if ((threadIdx.x & 63) == 0) red4[threadIdx.x >> 6] = v;
    __syncthreads();
    float r = red4[0] + red4[1] + red4[2] + red4[3];
    __syncthreads();
    return r;
}

// ---------------- fused layer-0 conversion + deg zero ----------------
__global__ __launch_bounds__(256) void conv_bf16_zero(const float* __restrict__ in, u16* __restrict__ out,
                                                      int n4, int* __restrict__ deg) {
    if (blockIdx.x < NB) {
        int z = blockIdx.x * 256 + threadIdx.x;
        if (z < Nn) deg[z] = 0;
    }
    int i = blockIdx.x * 256 + threadIdx.x;
    if (i >= n4) return;
    float4 v = ((const float4*)in)[i];
    ushort4 o;
    o.x = f2bf(v.x); o.y = f2bf(v.y); o.z = f2bf(v.z); o.w = f2bf(v.w);
    ((ushort4*)out)[i] = o;
}

// ---------------- all weight prep in ONE kernel ----------------
// tasks (blockIdx.y): 0-2 attW[i]^T -> wt1[i] (bf16 [512][fin]); 3-5 linW[i]^T -> wt2[i] ([256][512]);
// 6-8 wvec[i][k][4] = {W[k]·asrc_h0, W[k]·asrc_h1, W[k]·adst_h0, W[k]·adst_h1}
struct PrepArgs {
    const float* attW[3]; const float* linW[3];
    const float* asrc[3]; const float* adst[3];
    u16* wt1[3]; u16* wt2[3]; float* wvec;   // wvec: [3][256][4]
    int fin[3];
};

__global__ __launch_bounds__(256) void prep_weights(PrepArgs a) {
    __shared__ float tile[32][33];
    int task = blockIdx.y, bx = blockIdx.x, t = threadIdx.x;
    if (task < 3) {                       // attW[i]: [K=fin][N=512] -> out [512][fin]
        int i = task, K = a.fin[i];
        int nb = bx & 15, kb = bx >> 4;
        if (kb * 32 >= K) return;
        int n0 = nb * 32, k0 = kb * 32;
        int tx = t & 31, ty = t >> 5;
        const float* in = a.attW[i];
        u16* out = a.wt1[i];
#pragma unroll
        for (int j = 0; j < 32; j += 8) tile[ty + j][tx] = in[(size_t)(k0 + ty + j) * 512 + n0 + tx];
        __syncthreads();
#pragma unroll
        for (int j = 0; j < 32; j += 8) out[(size_t)(n0 + ty + j) * K + k0 + tx] = f2bf(tile[tx][ty + j]);
    } else if (task < 6) {                // linW[i]: [512][256] -> out [256][512]
        int i = task - 3;
        int nb = bx & 7, kb = bx >> 3;
        if (kb >= 16) return;
        int n0 = nb * 32, k0 = kb * 32;
        int tx = t & 31, ty = t >> 5;
        const float* in = a.linW[i];
        u16* out = a.wt2[i];
#pragma unroll
        for (int j = 0; j < 32; j += 8) tile[ty + j][tx] = in[(size_t)(k0 + ty + j) * 256 + n0 + tx];
        __syncthreads();
#pragma unroll
        for (int j = 0; j < 32; j += 8) out[(size_t)(n0 + ty + j) * 512 + k0 + tx] = f2bf(tile[tx][ty + j]);
    } else {                              // wvec fold
        int i = task - 6, k = bx;
        if (k >= a.fin[i]) return;
        volatile float* red4 = &tile[0][0];
        const float* W = a.attW[i];
        float w0 = W[(size_t)k * HE + t];
        float w1 = W[(size_t)k * HE + EMB + t];
        float s0 = block_sum4(w0 * a.asrc[i][t], red4);
        float s1 = block_sum4(w1 * a.asrc[i][EMB + t], red4);
        float d0 = block_sum4(w0 * a.adst[i][t], red4);
        float d1 = block_sum4(w1 * a.adst[i][EMB + t], red4);
        if (t == 0) {
            float* wv = a.wvec + i * 1024 + k * 4;
            wv[0] = s0; wv[1] = s1; wv[2] = d0; wv[3] = d1;
        }
    }
}

// ---------------- edge preprocessing ----------------
__global__ __launch_bounds__(256) void edge_hist(const int* __restrict__ ei, int* __restrict__ deg) {
    int e = blockIdx.x * 256 + threadIdx.x;
    if (e >= ET) return;
    int d = (e < Ee) ? ei[Ee + e] : (e - Ee);
    atomicAdd(&deg[d], 1);
}

__global__ __launch_bounds__(256) void scan_blocks(const int* __restrict__ deg, int* __restrict__ incl,
                                                   int* __restrict__ bsum) {
    __shared__ int buf[256];
    int i = blockIdx.x * 256 + threadIdx.x;
    int v = (i < Nn) ? deg[i] : 0;
    buf[threadIdx.x] = v;
    __syncthreads();
    for (int off = 1; off < 256; off <<= 1) {
        int add = (threadIdx.x >= off) ? buf[threadIdx.x - off] : 0;
        __syncthreads();
        buf[threadIdx.x] += add;
        __syncthreads();
    }
    if (i < Nn) incl[i] = buf[threadIdx.x];
    if (threadIdx.x == 255) bsum[blockIdx.x] = buf[255];
}

// block 0: exclusive scan of NB block sums; block 1: group offsets by binary search
__global__ __launch_bounds__(256) void scan_tops_groups(const int* __restrict__ bsum, int* __restrict__ boff,
                                                        const int* __restrict__ batch, int* __restrict__ gptr) {
    if (blockIdx.x == 0) {
        __shared__ int buf[128];
        int t = threadIdx.x;
        if (t < 128) buf[t] = (t < NB) ? bsum[t] : 0;
        __syncthreads();
        for (int off = 1; off < 128; off <<= 1) {
            int add = 0;
            if (t < 128 && t >= off) add = buf[t - off];
            __syncthreads();
            if (t < 128) buf[t] += add;
            __syncthreads();
        }
        if (t < NB) boff[t] = (t == 0) ? 0 : buf[t - 1];
    } else {
        int g = threadIdx.x;
        if (g > NG) return;
        int lo = 0, hi = Nn;
        while (lo < hi) {
            int mid = (lo + hi) >> 1;
            if (batch[mid] < g) lo = mid + 1; else hi = mid;
        }
        gptr[g] = lo;
    }
}

// rowptr (exclusive) + cursor init in one pass
__global__ __launch_bounds__(256) void scan_add_cursor(const int* __restrict__ incl, const int* __restrict__ boff,
                                                       const int* __restrict__ deg, int* __restrict__ rowptr,
                                                       int* __restrict__ cursor) {
    int i = blockIdx.x * 256 + threadIdx.x;
    if (i < Nn) {
        int inc = incl[i] + boff[blockIdx.x];
        rowptr[i + 1] = inc;
        cursor[i] = inc - deg[i];
    }
    if (i == 0) rowptr[0] = 0;
}

__global__ __launch_bounds__(256) void edge_scatter(const int* __restrict__ ei, int* __restrict__ cursor,
                                                    int* __restrict__ colv) {
    int e = blockIdx.x * 256 + threadIdx.x;
    if (e >= ET) return;
    int s, d;
    if (e < Ee) { s = ei[e]; d = ei[Ee + e]; }
    else        { s = d = e - Ee; }
    int pos = atomicAdd(&cursor[d], 1);
    colv[pos] = s;
}

// ---------------- bf16 MFMA GEMM: C[M,N] = A[M,K] @ Bt[N,K]^T  (m97 structure) ----------------
#define GL_LDS(gsrc, ldst)                                                               \
    __builtin_amdgcn_global_load_lds(                                                    \
        (const __attribute__((address_space(1))) void*)(unsigned long long)(gsrc),       \
        (__attribute__((address_space(3))) void*)(unsigned)(unsigned long long)(ldst),   \
        16, 0, 0)

__global__ __launch_bounds__(256) void gemm_bf16(const u16* __restrict__ A, const u16* __restrict__ Bt,
                                                 float* __restrict__ C, const float* __restrict__ bias,
                                                 u16* __restrict__ Cb, int M, int N, int K, int relu) {
    __shared__ alignas(16) char sA[8192];  // [128 rows][32 k] bf16, row stride 64 B
    __shared__ alignas(16) char sB[8192];  // [128 cols][32 k] bf16
    int tid = threadIdx.x, lane = tid & 63, wid = tid >> 6;
    int l15 = lane & 15, q = lane >> 4;
    int row0 = blockIdx.y * 128, col0 = blockIdx.x * 128;
    int wrow = (wid >> 1) * 64, wcol = (wid & 1) * 64;

    f32x4 acc[4][4];
#pragma unroll
    for (int m = 0; m < 4; m++)
#pragma unroll
        for (int n = 0; n < 4; n++)
#pragma unroll
            for (int e = 0; e < 4; e++) acc[m][n][e] = 0.f;

    for (int k0 = 0; k0 < K; k0 += 32) {
#pragma unroll
        for (int is = 0; is < 2; ++is) {
            int base = is * 4096 + wid * 1024;
            int o = base + lane * 16;
            int row = o >> 6, kb = o & 63;
            int gr = row0 + row; gr = gr < M ? gr : M - 1;  // clamp tail (results discarded)
            const char* src = (const char*)(A + (size_t)gr * K + k0) + kb;
            GL_LDS(src, sA + base);
        }
#pragma unroll
        for (int is = 0; is < 2; ++is) {
            int base = is * 4096 + wid * 1024;
            int o = base + lane * 16;
            int row = o >> 6, kb = o & 63;
            const char* src = (const char*)(Bt + (size_t)(col0 + row) * K + k0) + kb;
            GL_LDS(src, sB + base);
        }
        __syncthreads();

        bf16x8 af[4], bfr[4];
#pragma unroll
        for (int m = 0; m < 4; m++)
            af[m] = *(const bf16x8*)(sA + ((wrow + m * 16 + l15) << 6) + q * 16);
#pragma unroll
        for (int n = 0; n < 4; n++)
            bfr[n] = *(const bf16x8*)(sB + ((wcol + n * 16 + l15) << 6) + q * 16);
#pragma unroll
        for (int m = 0; m < 4; m++)
#pragma unroll
            for (int n = 0; n < 4; n++)
                acc[m][n] = __builtin_amdgcn_mfma_f32_16x16x32_bf16(af[m], bfr[n], acc[m][n], 0, 0, 0);
        __syncthreads();
    }

    // epilogue: D row = (lane>>4)*4 + reg, col = lane&15
#pragma unroll
    for (int m = 0; m < 4; m++) {
        int rbase = row0 + wrow + m * 16 + q * 4;
#pragma unroll
        for (int reg = 0; reg < 4; reg++) {
            int r = rbase + reg;
            if (r >= M) continue;
#pragma unroll
            for (int n = 0; n < 4; n++) {
                int c = col0 + wcol + n * 16 + l15;
                float v = acc[m][n][reg] + (bias ? bias[c] : 0.f);
                if (relu) v = fmaxf(v, 0.f);
                if (C)  C[(size_t)r * N + c] = v;
                if (Cb) Cb[(size_t)r * N + c] = f2bf(v);
            }
        }
    }
}

// ---------------- attention logits: wave per node, al = Xb[n,:] @ wvec ----------------
__global__ __launch_bounds__(256) void compute_al_fused(const u16* __restrict__ Xb, const float* __restrict__ wvec,
                                                        float* __restrict__ alsrc, float* __restrict__ aldst,
                                                        int fin) {
    int n = blockIdx.x * 4 + (threadIdx.x >> 6);
    int lane = threadIdx.x & 63;
    float s0 = 0.f, s1 = 0.f, d0 = 0.f, d1 = 0.f;
    for (int j = lane; j < fin; j += 64) {
        float x = bf2f(Xb[(size_t)n * fin + j]);
        float4 w = *(const float4*)(wvec + j * 4);
        s0 += x * w.x; s1 += x * w.y; d0 += x * w.z; d1 += x * w.w;
    }
#pragma unroll
    for (int off = 32; off > 0; off >>= 1) {
        s0 += __shfl_xor(s0, off, 64); s1 += __shfl_xor(s1, off, 64);
        d0 += __shfl_xor(d0, off, 64); d1 += __shfl_xor(d1, off, 64);
    }
    if (lane == 0) {
        alsrc[n * 2 + 0] = s0; alsrc[n * 2 + 1] = s1;
        aldst[n * 2 + 0] = d0; aldst[n * 2 + 1] = d1;
    }
}

__device__ __forceinline__ float lrelu(float x) { return x >= 0.f ? x : SLOPE * x; }

// ---------------- CSR attention + aggregation (wave per dst, 4 dst/block) ----------------
__global__ __launch_bounds__(256) void attn_aggregate(const u16* __restrict__ Hb,
                                                      const float* __restrict__ alsrc,
                                                      const float* __restrict__ aldst,
                                                      const int* __restrict__ row_ptr,
                                                      const int* __restrict__ colv,
                                                      const float* __restrict__ bias,
                                                      u16* __restrict__ Yb) {
    int d = blockIdx.x * 4 + (threadIdx.x >> 6);
    int lane = threadIdx.x & 63;
    int h = lane >> 5;
    float ad = aldst[d * 2 + h];
    int beg = row_ptr[d], end = row_ptr[d + 1];
    float S = 0.f;
    float acc[8] = {};

    int k = beg;
    for (; k + 3 < end; k += 4) {
        int s0 = colv[k], s1 = colv[k + 1], s2 = colv[k + 2], s3 = colv[k + 3];
        float e0 = __expf(lrelu(alsrc[s0 * 2 + h] + ad));
        float e1 = __expf(lrelu(alsrc[s1 * 2 + h] + ad));
        float e2 = __expf(lrelu(alsrc[s2 * 2 + h] + ad));
        float e3 = __expf(lrelu(alsrc[s3 * 2 + h] + ad));
        bf16x8 v0 = *(const bf16x8*)(Hb + (size_t)s0 * HE + lane * 8);
        bf16x8 v1 = *(const bf16x8*)(Hb + (size_t)s1 * HE + lane * 8);
        bf16x8 v2 = *(const bf16x8*)(Hb + (size_t)s2 * HE + lane * 8);
        bf16x8 v3 = *(const bf16x8*)(Hb + (size_t)s3 * HE + lane * 8);
        S += (e0 + e1) + (e2 + e3);
#pragma unroll
        for (int j = 0; j < 8; j++)
            acc[j] += (e0 * bf2f((u16)v0[j]) + e1 * bf2f((u16)v1[j])) +
                      (e2 * bf2f((u16)v2[j]) + e3 * bf2f((u16)v3[j]));
    }
    for (; k < end; ++k) {
        int s0 = colv[k];
        float e0 = __expf(lrelu(alsrc[s0 * 2 + h] + ad));
        bf16x8 v0 = *(const bf16x8*)(Hb + (size_t)s0 * HE + lane * 8);
        S += e0;
#pragma unroll
        for (int j = 0; j < 8; j++) acc[j] += e0 * bf2f((u16)v0[j]);
    }

    float r = 1.f / S;
    bf16x8 o;
#pragma unroll
    for (int j = 0; j < 8; j++)
        o[j] = (short)f2bf(fmaxf(acc[j] * r + bias[lane * 8 + j], 0.f));
    *(bf16x8*)(Yb + (size_t)d * HE + lane * 8) = o;
}

// ---------------- pooling: one kernel, block per group, role-split max/mean ----------------
__global__ __launch_bounds__(512) void pool_fused(const u16* __restrict__ Xb, const int* __restrict__ gptr,
                                                  float* __restrict__ repsum, int accumulate) {
    int g = blockIdx.x, t = threadIdx.x;
    int f = t & 255, role = t >> 8;
    int beg = gptr[g], end = gptr[g + 1];
    float v;
    if (role == 0) {
        float mx = 0.f;
        for (int n = beg; n < end; ++n) mx = fmaxf(mx, bf2f(Xb[(size_t)n * EMB + f]));
        v = mx;
    } else {
        float sm = 0.f;
        for (int n = beg; n < end; ++n) sm += bf2f(Xb[(size_t)n * EMB + f]);
        int cnt = end - beg;
        v = sm / fmaxf((float)cnt, 1.f);
    }
    int idx = g * 512 + role * EMB + f;
    if (accumulate) repsum[idx] += v; else repsum[idx] = v;
}

// ---------------- fused head: g1 = relu(repsum@l1W+b); out = g1@l2W+b ----------------
__global__ __launch_bounds__(512) void head_fused(const float* __restrict__ repsum, const float* __restrict__ l1W,
                                                  const float* __restrict__ l1b, const float* __restrict__ l2W,
                                                  const float* __restrict__ l2b, float* __restrict__ out) {
    __shared__ float row[512];
    __shared__ float gr[512];
    __shared__ float red[8];
    int r = blockIdx.x, t = threadIdx.x;
    row[t] = repsum[(size_t)r * 512 + t];
    __syncthreads();
    float acc = 0.f;
#pragma unroll 8
    for (int k = 0; k < 512; k++) acc += row[k] * l1W[(size_t)k * DENSE + t];
    gr[t] = fmaxf(acc + l1b[t], 0.f);
    __syncthreads();
#pragma unroll
    for (int c = 0; c < NCLS; c++) {
        float p = gr[t] * l2W[(size_t)t * NCLS + c];
        p = wave_sum(p);
        if ((t & 63) == 0) red[t >> 6] = p;
        __syncthreads();
        if (t == 0) {
            float s = 0.f;
#pragma unroll
            for (int i = 0; i < 8; i++) s += red[i];
            out[r * NCLS + c] = s + l2b[c];
        }
        __syncthreads();
    }
}

// ---------------- launch ----------------
extern "C" void kernel_launch(void* const* d_in, const int* in_sizes, int n_in,
                              void* d_out, int out_size, void* d_ws, size_t ws_size,
                              hipStream_t stream) {
    const float* x_in  = (const float*)d_in[0];
    const int*   ei    = (const int*)d_in[1];
    const int*   batch = (const int*)d_in[2];
    const float* attW[3] = {(const float*)d_in[3],  (const float*)d_in[9],  (const float*)d_in[15]};
    const float* asrc[3] = {(const float*)d_in[4],  (const float*)d_in[10], (const float*)d_in[16]};
    const float* adst[3] = {(const float*)d_in[5],  (const float*)d_in[11], (const float*)d_in[17]};
    const float* attB[3] = {(const float*)d_in[6],  (const float*)d_in[12], (const float*)d_in[18]};
    const float* linW[3] = {(const float*)d_in[7],  (const float*)d_in[13], (const float*)d_in[19]};
    const float* linB[3] = {(const float*)d_in[8],  (const float*)d_in[14], (const float*)d_in[20]};
    const float* l1W = (const float*)d_in[21];
    const float* l1b = (const float*)d_in[22];
    const float* l2W = (const float*)d_in[23];
    const float* l2b = (const float*)d_in[24];
    float* out = (float*)d_out;

    char* ws = (char*)d_ws;
    size_t off = 0;
    auto alloc = [&](size_t bytes) -> void* {
        void* p = ws + off;
        off += (bytes + 255) & ~(size_t)255;
        return p;
    };
    u16*   Hb     = (u16*)alloc((size_t)Nn * HE * 2);
    u16*   Xb     = (u16*)alloc((size_t)Nn * EMB * 2);
    u16*   Yb     = (u16*)alloc((size_t)Nn * HE * 2);
    u16*   wt1[3], *wt2[3];
    for (int i = 0; i < 3; i++) {
        wt1[i] = (u16*)alloc((size_t)512 * 512 * 2);
        wt2[i] = (u16*)alloc((size_t)256 * 512 * 2);
    }
    float* wvec   = (float*)alloc((size_t)3 * 256 * 4 * 4);
    float* alsrc  = (float*)alloc((size_t)Nn * 2 * 4);
    float* aldst  = (float*)alloc((size_t)Nn * 2 * 4);
    int*   deg    = (int*)alloc((size_t)Nn * 4);
    int*   incl   = (int*)alloc((size_t)Nn * 4);
    int*   bsum   = (int*)alloc((size_t)NB * 4);
    int*   boff   = (int*)alloc((size_t)NB * 4);
    int*   rowptr = (int*)alloc((size_t)(Nn + 1) * 4);
    int*   cursor = (int*)alloc((size_t)Nn * 4);
    int*   colv   = (int*)alloc((size_t)ET * 4);
    int*   gptr   = (int*)alloc((size_t)(NG + 1) * 4);
    float* repsum = (float*)alloc((size_t)NG * 512 * 4);

    // ---- prologue: input conversion (+deg zero), weight prep ----
    conv_bf16_zero<<<(Nn * 128 / 4 + 255) / 256, 256, 0, stream>>>(x_in, Xb, Nn * 128 / 4, deg);

    PrepArgs pa;
    for (int i = 0; i < 3; i++) {
        pa.attW[i] = attW[i]; pa.linW[i] = linW[i];
        pa.asrc[i] = asrc[i]; pa.adst[i] = adst[i];
        pa.wt1[i] = wt1[i];   pa.wt2[i] = wt2[i];
        pa.fin[i] = (i == 0) ? 128 : EMB;
    }
    pa.wvec = wvec;
    prep_weights<<<dim3(256, 9), 256, 0, stream>>>(pa);

    // ---- edge preprocessing (CSR by dst) ----
    edge_hist<<<(ET + 255) / 256, 256, 0, stream>>>(ei, deg);
    scan_blocks<<<NB, 256, 0, stream>>>(deg, incl, bsum);
    scan_tops_groups<<<2, 256, 0, stream>>>(bsum, boff, batch, gptr);
    scan_add_cursor<<<NB, 256, 0, stream>>>(incl, boff, deg, rowptr, cursor);
    edge_scatter<<<(ET + 255) / 256, 256, 0, stream>>>(ei, cursor, colv);

    // ---- layers ----
    for (int i = 0; i < 3; i++) {
        int fin = (i == 0) ? 128 : EMB;
        compute_al_fused<<<Nn / 4, 256, 0, stream>>>(Xb, wvec + i * 1024, alsrc, aldst, fin);
        gemm_bf16<<<dim3(512 / 128, (Nn + 127) / 128), 256, 0, stream>>>(
            Xb, wt1[i], nullptr, nullptr, Hb, Nn, 512, fin, 0);
        attn_aggregate<<<Nn / 4, 256, 0, stream>>>(Hb, alsrc, aldst, rowptr, colv, attB[i], Yb);
        gemm_bf16<<<dim3(256 / 128, (Nn + 127) / 128), 256, 0, stream>>>(
            Yb, wt2[i], nullptr, linB[i], Xb, Nn, 256, 512, 1);
        pool_fused<<<NG, 512, 0, stream>>>(Xb, gptr, repsum, i > 0 ? 1 : 0);
    }

    // ---- head ----
    head_fused<<<NG, 512, 0, stream>>>(repsum, l1W, l1b, l2W, l2b, out);
}

// Round 12
// 453.562 us; speedup vs baseline: 1.2236x; 1.2236x over previous
//
#include <hip/hip_runtime.h>

#define Nn 20000
#define Ee 240000
#define ET (Ee + Nn)        // 260000 edges incl self-loops
#define EMB 256
#define HE  512             // H * EMB
#define NG  128             // graphs
#define DENSE 512
#define NCLS 10
#define SLOPE 0.2f
#define NB 79               // ceil(Nn/256) scan blocks

typedef unsigned short u16;
typedef short bf16x8 __attribute__((ext_vector_type(8)));
typedef float f32x4 __attribute__((ext_vector_type(4)));

__device__ __forceinline__ u16 f2bf(float f) {
    unsigned u = __float_as_uint(f);
    unsigned r = (u + 0x7fffu + ((u >> 16) & 1u)) >> 16;
    return (u16)r;
}
__device__ __forceinline__ float bf2f(u16 u) {
    return __uint_as_float(((unsigned)u) << 16);
}

// ---------------- reduction helpers ----------------
__device__ __forceinline__ float wave_sum(float v) {
#pragma unroll
    for (int off = 32; off > 0; off >>= 1) v += __shfl_down(v, off, 64);
    return v;
}
__device__ __forceinline__ float block_sum4(float v, volatile float* red4) {
    v = wave_sum(v);
    if ((threadIdx.x & 63) == 0) red4[threadIdx.x >> 6] = v;
    __syncthreads();
    float r = red4[0] + red4[1] + red4[2] + red4[3];
    __syncthreads();
    return r;
}

// ---------------- fused layer-0 conversion + deg zero ----------------
__global__ __launch_bounds__(256) void conv_bf16_zero(const float* __restrict__ in, u16* __restrict__ out,
                                                      int n4, int* __restrict__ deg) {
    if (blockIdx.x < NB) {
        int z = blockIdx.x * 256 + threadIdx.x;
        if (z < Nn) deg[z] = 0;
    }
    int i = blockIdx.x * 256 + threadIdx.x;
    if (i >= n4) return;
    float4 v = ((const float4*)in)[i];
    ushort4 o;
    o.x = f2bf(v.x); o.y = f2bf(v.y); o.z = f2bf(v.z); o.w = f2bf(v.w);
    ((ushort4*)out)[i] = o;
}

// ---------------- all weight prep in ONE kernel ----------------
struct PrepArgs {
    const float* attW[3]; const float* linW[3];
    const float* asrc[3]; const float* adst[3];
    u16* wt1[3]; u16* wt2[3]; float* wvec;   // wvec: [3][256][4]
    int fin[3];
};

__global__ __launch_bounds__(256) void prep_weights(PrepArgs a) {
    __shared__ float tile[32][33];
    int task = blockIdx.y, bx = blockIdx.x, t = threadIdx.x;
    if (task < 3) {                       // attW[i]: [K=fin][N=512] -> out [512][fin]
        int i = task, K = a.fin[i];
        int nb = bx & 15, kb = bx >> 4;
        if (kb * 32 >= K) return;
        int n0 = nb * 32, k0 = kb * 32;
        int tx = t & 31, ty = t >> 5;
        const float* in = a.attW[i];
        u16* out = a.wt1[i];
#pragma unroll
        for (int j = 0; j < 32; j += 8) tile[ty + j][tx] = in[(size_t)(k0 + ty + j) * 512 + n0 + tx];
        __syncthreads();
#pragma unroll
        for (int j = 0; j < 32; j += 8) out[(size_t)(n0 + ty + j) * K + k0 + tx] = f2bf(tile[tx][ty + j]);
    } else if (task < 6) {                // linW[i]: [512][256] -> out [256][512]
        int i = task - 3;
        int nb = bx & 7, kb = bx >> 3;
        if (kb >= 16) return;
        int n0 = nb * 32, k0 = kb * 32;
        int tx = t & 31, ty = t >> 5;
        const float* in = a.linW[i];
        u16* out = a.wt2[i];
#pragma unroll
        for (int j = 0; j < 32; j += 8) tile[ty + j][tx] = in[(size_t)(k0 + ty + j) * 256 + n0 + tx];
        __syncthreads();
#pragma unroll
        for (int j = 0; j < 32; j += 8) out[(size_t)(n0 + ty + j) * 512 + k0 + tx] = f2bf(tile[tx][ty + j]);
    } else {                              // wvec fold: wvec[k] = {W[k]·asrc_h0, W[k]·asrc_h1, W[k]·adst_h0, W[k]·adst_h1}
        int i = task - 6, k = bx;
        if (k >= a.fin[i]) return;
        volatile float* red4 = &tile[0][0];
        const float* W = a.attW[i];
        float w0 = W[(size_t)k * HE + t];
        float w1 = W[(size_t)k * HE + EMB + t];
        float s0 = block_sum4(w0 * a.asrc[i][t], red4);
        float s1 = block_sum4(w1 * a.asrc[i][EMB + t], red4);
        float d0 = block_sum4(w0 * a.adst[i][t], red4);
        float d1 = block_sum4(w1 * a.adst[i][EMB + t], red4);
        if (t == 0) {
            float* wv = a.wvec + i * 1024 + k * 4;
            wv[0] = s0; wv[1] = s1; wv[2] = d0; wv[3] = d1;
        }
    }
}

// ---------------- edge preprocessing ----------------
__global__ __launch_bounds__(256) void edge_hist(const int* __restrict__ ei, int* __restrict__ deg) {
    int e = blockIdx.x * 256 + threadIdx.x;
    if (e >= ET) return;
    int d = (e < Ee) ? ei[Ee + e] : (e - Ee);
    atomicAdd(&deg[d], 1);
}

__global__ __launch_bounds__(256) void scan_blocks(const int* __restrict__ deg, int* __restrict__ incl,
                                                   int* __restrict__ bsum) {
    __shared__ int buf[256];
    int i = blockIdx.x * 256 + threadIdx.x;
    int v = (i < Nn) ? deg[i] : 0;
    buf[threadIdx.x] = v;
    __syncthreads();
    for (int off = 1; off < 256; off <<= 1) {
        int add = (threadIdx.x >= off) ? buf[threadIdx.x - off] : 0;
        __syncthreads();
        buf[threadIdx.x] += add;
        __syncthreads();
    }
    if (i < Nn) incl[i] = buf[threadIdx.x];
    if (threadIdx.x == 255) bsum[blockIdx.x] = buf[255];
}

// block 0: exclusive scan of NB block sums; block 1: group offsets by binary search
__global__ __launch_bounds__(256) void scan_tops_groups(const int* __restrict__ bsum, int* __restrict__ boff,
                                                        const int* __restrict__ batch, int* __restrict__ gptr) {
    if (blockIdx.x == 0) {
        __shared__ int buf[128];
        int t = threadIdx.x;
        if (t < 128) buf[t] = (t < NB) ? bsum[t] : 0;
        __syncthreads();
        for (int off = 1; off < 128; off <<= 1) {
            int add = 0;
            if (t < 128 && t >= off) add = buf[t - off];
            __syncthreads();
            if (t < 128) buf[t] += add;
            __syncthreads();
        }
        if (t < NB) boff[t] = (t == 0) ? 0 : buf[t - 1];
    } else {
        int g = threadIdx.x;
        if (g > NG) return;
        int lo = 0, hi = Nn;
        while (lo < hi) {
            int mid = (lo + hi) >> 1;
            if (batch[mid] < g) lo = mid + 1; else hi = mid;
        }
        gptr[g] = lo;
    }
}

// rowptr (exclusive) + cursor init in one pass
__global__ __launch_bounds__(256) void scan_add_cursor(const int* __restrict__ incl, const int* __restrict__ boff,
                                                       const int* __restrict__ deg, int* __restrict__ rowptr,
                                                       int* __restrict__ cursor) {
    int i = blockIdx.x * 256 + threadIdx.x;
    if (i < Nn) {
        int inc = incl[i] + boff[blockIdx.x];
        rowptr[i + 1] = inc;
        cursor[i] = inc - deg[i];
    }
    if (i == 0) rowptr[0] = 0;
}

__global__ __launch_bounds__(256) void edge_scatter(const int* __restrict__ ei, int* __restrict__ cursor,
                                                    int* __restrict__ colv) {
    int e = blockIdx.x * 256 + threadIdx.x;
    if (e >= ET) return;
    int s, d;
    if (e < Ee) { s = ei[e]; d = ei[Ee + e]; }
    else        { s = d = e - Ee; }
    int pos = atomicAdd(&cursor[d], 1);
    colv[pos] = s;
}

// ---------------- bf16 MFMA GEMM: C[M,N] = A[M,K] @ Bt[N,K]^T  (m97 structure) ----------------
// lda: A row stride (elements). aoff: added to A row offset when col0 >= 256 (per-head Z select).
#define GL_LDS(gsrc, ldst)                                                               \
    __builtin_amdgcn_global_load_lds(                                                    \
        (const __attribute__((address_space(1))) void*)(unsigned long long)(gsrc),       \
        (__attribute__((address_space(3))) void*)(unsigned)(unsigned long long)(ldst),   \
        16, 0, 0)

__global__ __launch_bounds__(256) void gemm_bf16(const u16* __restrict__ A, int lda, int aoff,
                                                 const u16* __restrict__ Bt, const float* __restrict__ bias,
                                                 u16* __restrict__ Cb, int M, int N, int K, int relu) {
    __shared__ alignas(16) char sA[8192];  // [128 rows][32 k] bf16, row stride 64 B
    __shared__ alignas(16) char sB[8192];  // [128 cols][32 k] bf16
    int tid = threadIdx.x, lane = tid & 63, wid = tid >> 6;
    int l15 = lane & 15, q = lane >> 4;
    int row0 = blockIdx.y * 128, col0 = blockIdx.x * 128;
    int wrow = (wid >> 1) * 64, wcol = (wid & 1) * 64;
    int ao = (col0 >= 256) ? aoff : 0;

    f32x4 acc[4][4];
#pragma unroll
    for (int m = 0; m < 4; m++)
#pragma unroll
        for (int n = 0; n < 4; n++)
#pragma unroll
            for (int e = 0; e < 4; e++) acc[m][n][e] = 0.f;

    for (int k0 = 0; k0 < K; k0 += 32) {
#pragma unroll
        for (int is = 0; is < 2; ++is) {
            int base = is * 4096 + wid * 1024;
            int o = base + lane * 16;
            int row = o >> 6, kb = o & 63;
            int gr = row0 + row; gr = gr < M ? gr : M - 1;  // clamp tail (results discarded)
            const char* src = (const char*)(A + (size_t)gr * lda + ao + k0) + kb;
            GL_LDS(src, sA + base);
        }
#pragma unroll
        for (int is = 0; is < 2; ++is) {
            int base = is * 4096 + wid * 1024;
            int o = base + lane * 16;
            int row = o >> 6, kb = o & 63;
            const char* src = (const char*)(Bt + (size_t)(col0 + row) * K + k0) + kb;
            GL_LDS(src, sB + base);
        }
        __syncthreads();

        bf16x8 af[4], bfr[4];
#pragma unroll
        for (int m = 0; m < 4; m++)
            af[m] = *(const bf16x8*)(sA + ((wrow + m * 16 + l15) << 6) + q * 16);
#pragma unroll
        for (int n = 0; n < 4; n++)
            bfr[n] = *(const bf16x8*)(sB + ((wcol + n * 16 + l15) << 6) + q * 16);
#pragma unroll
        for (int m = 0; m < 4; m++)
#pragma unroll
            for (int n = 0; n < 4; n++)
                acc[m][n] = __builtin_amdgcn_mfma_f32_16x16x32_bf16(af[m], bfr[n], acc[m][n], 0, 0, 0);
        __syncthreads();
    }

    // epilogue: D row = (lane>>4)*4 + reg, col = lane&15
#pragma unroll
    for (int m = 0; m < 4; m++) {
        int rbase = row0 + wrow + m * 16 + q * 4;
#pragma unroll
        for (int reg = 0; reg < 4; reg++) {
            int r = rbase + reg;
            if (r >= M) continue;
#pragma unroll
            for (int n = 0; n < 4; n++) {
                int c = col0 + wcol + n * 16 + l15;
                float v = acc[m][n][reg] + (bias ? bias[c] : 0.f);
                if (relu) v = fmaxf(v, 0.f);
                Cb[(size_t)r * N + c] = f2bf(v);
            }
        }
    }
}

// ---------------- attention logits: wave per node, al = Xb[n,:] @ wvec ----------------
__global__ __launch_bounds__(256) void compute_al_fused(const u16* __restrict__ Xb, const float* __restrict__ wvec,
                                                        float* __restrict__ alsrc, float* __restrict__ aldst,
                                                        int fin) {
    int n = blockIdx.x * 4 + (threadIdx.x >> 6);
    int lane = threadIdx.x & 63;
    float s0 = 0.f, s1 = 0.f, d0 = 0.f, d1 = 0.f;
    for (int j = lane; j < fin; j += 64) {
        float x = bf2f(Xb[(size_t)n * fin + j]);
        float4 w = *(const float4*)(wvec + j * 4);
        s0 += x * w.x; s1 += x * w.y; d0 += x * w.z; d1 += x * w.w;
    }
#pragma unroll
    for (int off = 32; off > 0; off >>= 1) {
        s0 += __shfl_xor(s0, off, 64); s1 += __shfl_xor(s1, off, 64);
        d0 += __shfl_xor(d0, off, 64); d1 += __shfl_xor(d1, off, 64);
    }
    if (lane == 0) {
        alsrc[n * 2 + 0] = s0; alsrc[n * 2 + 1] = s1;
        aldst[n * 2 + 0] = d0; aldst[n * 2 + 1] = d1;
    }
}

__device__ __forceinline__ float lrelu(float x) { return x >= 0.f ? x : SLOPE * x; }

// ---------------- aggregate-then-transform: Z_h[d] = sum_s alpha_h(s,d) X[s] ----------------
// Wave per dst (4/block). Lane owns FIN/64 features of X; both heads accumulated from one row read.
// Zb row layout: [head0 FIN][head1 FIN] (2*FIN bf16).
template <int FIN>
__global__ __launch_bounds__(256) void attn_agg_x(const u16* __restrict__ Xb,
                                                  const float* __restrict__ alsrc,
                                                  const float* __restrict__ aldst,
                                                  const int* __restrict__ row_ptr,
                                                  const int* __restrict__ colv,
                                                  u16* __restrict__ Zb) {
    constexpr int FPL = FIN / 64;
    int d = blockIdx.x * 4 + (threadIdx.x >> 6);
    int lane = threadIdx.x & 63;
    float ad0 = aldst[d * 2 + 0], ad1 = aldst[d * 2 + 1];
    int beg = row_ptr[d], end = row_ptr[d + 1];
    float S0 = 0.f, S1 = 0.f;
    float a0[FPL] = {}, a1[FPL] = {};

    int k = beg;
    for (; k + 1 < end; k += 2) {
        int s0 = colv[k], s1 = colv[k + 1];
        float2 l0 = *(const float2*)(alsrc + s0 * 2);
        float2 l1 = *(const float2*)(alsrc + s1 * 2);
        float e00 = __expf(lrelu(l0.x + ad0)), e01 = __expf(lrelu(l0.y + ad1));
        float e10 = __expf(lrelu(l1.x + ad0)), e11 = __expf(lrelu(l1.y + ad1));
        u16 v0[FPL], v1[FPL];
        if constexpr (FPL == 4) {
            *(ushort4*)v0 = *(const ushort4*)(Xb + (size_t)s0 * FIN + lane * 4);
            *(ushort4*)v1 = *(const ushort4*)(Xb + (size_t)s1 * FIN + lane * 4);
        } else {
            *(ushort2*)v0 = *(const ushort2*)(Xb + (size_t)s0 * FIN + lane * 2);
            *(ushort2*)v1 = *(const ushort2*)(Xb + (size_t)s1 * FIN + lane * 2);
        }
        S0 += e00 + e10; S1 += e01 + e11;
#pragma unroll
        for (int j = 0; j < FPL; j++) {
            float x0 = bf2f(v0[j]), x1 = bf2f(v1[j]);
            a0[j] += e00 * x0 + e10 * x1;
            a1[j] += e01 * x0 + e11 * x1;
        }
    }
    if (k < end) {
        int s0 = colv[k];
        float2 l0 = *(const float2*)(alsrc + s0 * 2);
        float e00 = __expf(lrelu(l0.x + ad0)), e01 = __expf(lrelu(l0.y + ad1));
        u16 v0[FPL];
        if constexpr (FPL == 4) *(ushort4*)v0 = *(const ushort4*)(Xb + (size_t)s0 * FIN + lane * 4);
        else                    *(ushort2*)v0 = *(const ushort2*)(Xb + (size_t)s0 * FIN + lane * 2);
        S0 += e00; S1 += e01;
#pragma unroll
        for (int j = 0; j < FPL; j++) {
            float x0 = bf2f(v0[j]);
            a0[j] += e00 * x0;
            a1[j] += e01 * x0;
        }
    }

    float r0 = 1.f / S0, r1 = 1.f / S1;
    u16 o0[FPL], o1[FPL];
#pragma unroll
    for (int j = 0; j < FPL; j++) { o0[j] = f2bf(a0[j] * r0); o1[j] = f2bf(a1[j] * r1); }
    u16* q = Zb + (size_t)d * (2 * FIN);
    if constexpr (FPL == 4) {
        *(ushort4*)(q + lane * 4)       = *(ushort4*)o0;
        *(ushort4*)(q + FIN + lane * 4) = *(ushort4*)o1;
    } else {
        *(ushort2*)(q + lane * 2)       = *(ushort2*)o0;
        *(ushort2*)(q + FIN + lane * 2) = *(ushort2*)o1;
    }
}

// ---------------- pooling (2-stage, bf16 input) ----------------
#define PS 8
__global__ __launch_bounds__(256) void pool_partial(const u16* __restrict__ Xb, const int* __restrict__ gptr,
                                                    float* __restrict__ pmax, float* __restrict__ psum) {
    int g = blockIdx.x, sb = blockIdx.y, t = threadIdx.x;
    int beg = gptr[g], end = gptr[g + 1];
    float mx = 0.f, sm = 0.f;  // X is post-relu (>=0)
    for (int n = beg + sb; n < end; n += PS) {
        float v = bf2f(Xb[(size_t)n * EMB + t]);
        mx = fmaxf(mx, v);
        sm += v;
    }
    pmax[((size_t)sb * NG + g) * EMB + t] = mx;
    psum[((size_t)sb * NG + g) * EMB + t] = sm;
}

__global__ __launch_bounds__(256) void pool_final(const float* __restrict__ pmax, const float* __restrict__ psum,
                                                  const int* __restrict__ gptr, float* __restrict__ repsum,
                                                  int accumulate) {
    int idx = blockIdx.x * 256 + threadIdx.x;
    int g = idx >> 9, f = idx & 511;
    float r;
    if (f < EMB) {
        float mx = 0.f;
        for (int s = 0; s < PS; s++) mx = fmaxf(mx, pmax[((size_t)s * NG + g) * EMB + f]);
        r = mx;
    } else {
        int f2 = f - EMB;
        float sm = 0.f;
        for (int s = 0; s < PS; s++) sm += psum[((size_t)s * NG + g) * EMB + f2];
        int cnt = gptr[g + 1] - gptr[g];
        r = sm / fmaxf((float)cnt, 1.f);
    }
    if (accumulate) repsum[idx] += r; else repsum[idx] = r;
}

// ---------------- fused head: g1 = relu(repsum@l1W+b); out = g1@l2W+b ----------------
__global__ __launch_bounds__(512) void head_fused(const float* __restrict__ repsum, const float* __restrict__ l1W,
                                                  const float* __restrict__ l1b, const float* __restrict__ l2W,
                                                  const float* __restrict__ l2b, float* __restrict__ out) {
    __shared__ float row[512];
    __shared__ float gr[512];
    __shared__ float red[8];
    int r = blockIdx.x, t = threadIdx.x;
    row[t] = repsum[(size_t)r * 512 + t];
    __syncthreads();
    float acc = 0.f;
#pragma unroll 8
    for (int k = 0; k < 512; k++) acc += row[k] * l1W[(size_t)k * DENSE + t];
    gr[t] = fmaxf(acc + l1b[t], 0.f);
    __syncthreads();
#pragma unroll
    for (int c = 0; c < NCLS; c++) {
        float p = gr[t] * l2W[(size_t)t * NCLS + c];
        p = wave_sum(p);
        if ((t & 63) == 0) red[t >> 6] = p;
        __syncthreads();
        if (t == 0) {
            float s = 0.f;
#pragma unroll
            for (int i = 0; i < 8; i++) s += red[i];
            out[r * NCLS + c] = s + l2b[c];
        }
        __syncthreads();
    }
}

// ---------------- launch ----------------
extern "C" void kernel_launch(void* const* d_in, const int* in_sizes, int n_in,
                              void* d_out, int out_size, void* d_ws, size_t ws_size,
                              hipStream_t stream) {
    const float* x_in  = (const float*)d_in[0];
    const int*   ei    = (const int*)d_in[1];
    const int*   batch = (const int*)d_in[2];
    const float* attW[3] = {(const float*)d_in[3],  (const float*)d_in[9],  (const float*)d_in[15]};
    const float* asrc[3] = {(const float*)d_in[4],  (const float*)d_in[10], (const float*)d_in[16]};
    const float* adst[3] = {(const float*)d_in[5],  (const float*)d_in[11], (const float*)d_in[17]};
    const float* attB[3] = {(const float*)d_in[6],  (const float*)d_in[12], (const float*)d_in[18]};
    const float* linW[3] = {(const float*)d_in[7],  (const float*)d_in[13], (const float*)d_in[19]};
    const float* linB[3] = {(const float*)d_in[8],  (const float*)d_in[14], (const float*)d_in[20]};
    const float* l1W = (const float*)d_in[21];
    const float* l1b = (const float*)d_in[22];
    const float* l2W = (const float*)d_in[23];
    const float* l2b = (const float*)d_in[24];
    float* out = (float*)d_out;

    char* ws = (char*)d_ws;
    size_t off = 0;
    auto alloc = [&](size_t bytes) -> void* {
        void* p = ws + off;
        off += (bytes + 255) & ~(size_t)255;
        return p;
    };
    u16*   Zb     = (u16*)alloc((size_t)Nn * HE * 2);   // aggregated X per head: [Nn][2*fin]
    u16*   Xb     = (u16*)alloc((size_t)Nn * EMB * 2);
    u16*   Yb     = (u16*)alloc((size_t)Nn * HE * 2);
    u16*   wt1[3], *wt2[3];
    for (int i = 0; i < 3; i++) {
        wt1[i] = (u16*)alloc((size_t)512 * 512 * 2);
        wt2[i] = (u16*)alloc((size_t)256 * 512 * 2);
    }
    float* wvec   = (float*)alloc((size_t)3 * 256 * 4 * 4);
    float* alsrc  = (float*)alloc((size_t)Nn * 2 * 4);
    float* aldst  = (float*)alloc((size_t)Nn * 2 * 4);
    int*   deg    = (int*)alloc((size_t)Nn * 4);
    int*   incl   = (int*)alloc((size_t)Nn * 4);
    int*   bsum   = (int*)alloc((size_t)NB * 4);
    int*   boff   = (int*)alloc((size_t)NB * 4);
    int*   rowptr = (int*)alloc((size_t)(Nn + 1) * 4);
    int*   cursor = (int*)alloc((size_t)Nn * 4);
    int*   colv   = (int*)alloc((size_t)ET * 4);
    int*   gptr   = (int*)alloc((size_t)(NG + 1) * 4);
    float* pmax   = (float*)alloc((size_t)PS * NG * EMB * 4);
    float* psum   = (float*)alloc((size_t)PS * NG * EMB * 4);
    float* repsum = (float*)alloc((size_t)NG * 512 * 4);

    // ---- prologue: input conversion (+deg zero), weight prep ----
    conv_bf16_zero<<<(Nn * 128 / 4 + 255) / 256, 256, 0, stream>>>(x_in, Xb, Nn * 128 / 4, deg);

    PrepArgs pa;
    for (int i = 0; i < 3; i++) {
        pa.attW[i] = attW[i]; pa.linW[i] = linW[i];
        pa.asrc[i] = asrc[i]; pa.adst[i] = adst[i];
        pa.wt1[i] = wt1[i];   pa.wt2[i] = wt2[i];
        pa.fin[i] = (i == 0) ? 128 : EMB;
    }
    pa.wvec = wvec;
    prep_weights<<<dim3(256, 9), 256, 0, stream>>>(pa);

    // ---- edge preprocessing (CSR by dst) ----
    edge_hist<<<(ET + 255) / 256, 256, 0, stream>>>(ei, deg);
    scan_blocks<<<NB, 256, 0, stream>>>(deg, incl, bsum);
    scan_tops_groups<<<2, 256, 0, stream>>>(bsum, boff, batch, gptr);
    scan_add_cursor<<<NB, 256, 0, stream>>>(incl, boff, deg, rowptr, cursor);
    edge_scatter<<<(ET + 255) / 256, 256, 0, stream>>>(ei, cursor, colv);

    // ---- layers: al -> aggregate X -> Z@W1 (+attB, relu) -> Y@W2 (+linB, relu) -> pool ----
    for (int i = 0; i < 3; i++) {
        int fin = (i == 0) ? 128 : EMB;
        compute_al_fused<<<Nn / 4, 256, 0, stream>>>(Xb, wvec + i * 1024, alsrc, aldst, fin);
        if (fin == 128)
            attn_agg_x<128><<<Nn / 4, 256, 0, stream>>>(Xb, alsrc, aldst, rowptr, colv, Zb);
        else
            attn_agg_x<256><<<Nn / 4, 256, 0, stream>>>(Xb, alsrc, aldst, rowptr, colv, Zb);
        gemm_bf16<<<dim3(512 / 128, (Nn + 127) / 128), 256, 0, stream>>>(
            Zb, 2 * fin, fin, wt1[i], attB[i], Yb, Nn, 512, fin, 1);
        gemm_bf16<<<dim3(256 / 128, (Nn + 127) / 128), 256, 0, stream>>>(
            Yb, 512, 0, wt2[i], linB[i], Xb, Nn, 256, 512, 1);
        pool_partial<<<dim3(NG, PS), 256, 0, stream>>>(Xb, gptr, pmax, psum);
        pool_final<<<(NG * 512) / 256, 256, 0, stream>>>(pmax, psum, gptr, repsum, i > 0 ? 1 : 0);
    }

    // ---- head ----
    head_fused<<<NG, 512, 0, stream>>>(repsum, l1W, l1b, l2W, l2b, out);
}

// Round 13
// 438.926 us; speedup vs baseline: 1.2644x; 1.0333x over previous
//
#include <hip/hip_runtime.h>

#define Nn 20000
#define Ee 240000
#define ET (Ee + Nn)        // 260000 edges incl self-loops
#define EMB 256
#define HE  512             // H * EMB
#define NG  128             // graphs
#define DENSE 512
#define NCLS 10
#define SLOPE 0.2f
#define NB 79               // ceil(Nn/256) scan blocks
#define PS 8                // pool sub-blocks per group

typedef unsigned short u16;
typedef short bf16x8 __attribute__((ext_vector_type(8)));
typedef float f32x4 __attribute__((ext_vector_type(4)));

__device__ __forceinline__ u16 f2bf(float f) {
    unsigned u = __float_as_uint(f);
    unsigned r = (u + 0x7fffu + ((u >> 16) & 1u)) >> 16;
    return (u16)r;
}
__device__ __forceinline__ float bf2f(u16 u) {
    return __uint_as_float(((unsigned)u) << 16);
}

// ---------------- reduction helpers ----------------
__device__ __forceinline__ float wave_sum(float v) {
#pragma unroll
    for (int off = 32; off > 0; off >>= 1) v += __shfl_down(v, off, 64);
    return v;
}
__device__ __forceinline__ float block_sum4(float v, volatile float* red4) {
    v = wave_sum(v);
    if ((threadIdx.x & 63) == 0) red4[threadIdx.x >> 6] = v;
    __syncthreads();
    float r = red4[0] + red4[1] + red4[2] + red4[3];
    __syncthreads();
    return r;
}

// ---------------- fused layer-0 conversion + deg zero + pool-buffer zero ----------------
// poolbuf: [3*128*256 pmax][128*256 psum] = 131072 floats, zeroed by blocks 1000..1511.
__global__ __launch_bounds__(256) void conv_bf16_zero(const float* __restrict__ in, u16* __restrict__ out,
                                                      int n4, int* __restrict__ deg,
                                                      float* __restrict__ poolbuf) {
    if (blockIdx.x < NB) {
        int z = blockIdx.x * 256 + threadIdx.x;
        if (z < Nn) deg[z] = 0;
    }
    if (blockIdx.x >= 1000 && blockIdx.x < 1512) {
        int z = (blockIdx.x - 1000) * 256 + threadIdx.x;   // 0..131071
        poolbuf[z] = 0.f;
    }
    int i = blockIdx.x * 256 + threadIdx.x;
    if (i >= n4) return;
    float4 v = ((const float4*)in)[i];
    ushort4 o;
    o.x = f2bf(v.x); o.y = f2bf(v.y); o.z = f2bf(v.z); o.w = f2bf(v.w);
    ((ushort4*)out)[i] = o;
}

// ---------------- all weight prep in ONE kernel ----------------
struct PrepArgs {
    const float* attW[3]; const float* linW[3];
    const float* asrc[3]; const float* adst[3];
    u16* wt1[3]; u16* wt2[3]; float* wvec;   // wvec: [3][256][4]
    int fin[3];
};

__global__ __launch_bounds__(256) void prep_weights(PrepArgs a) {
    __shared__ float tile[32][33];
    int task = blockIdx.y, bx = blockIdx.x, t = threadIdx.x;
    if (task < 3) {                       // attW[i]: [K=fin][N=512] -> out [512][fin]
        int i = task, K = a.fin[i];
        int nb = bx & 15, kb = bx >> 4;
        if (kb * 32 >= K) return;
        int n0 = nb * 32, k0 = kb * 32;
        int tx = t & 31, ty = t >> 5;
        const float* in = a.attW[i];
        u16* out = a.wt1[i];
#pragma unroll
        for (int j = 0; j < 32; j += 8) tile[ty + j][tx] = in[(size_t)(k0 + ty + j) * 512 + n0 + tx];
        __syncthreads();
#pragma unroll
        for (int j = 0; j < 32; j += 8) out[(size_t)(n0 + ty + j) * K + k0 + tx] = f2bf(tile[tx][ty + j]);
    } else if (task < 6) {                // linW[i]: [512][256] -> out [256][512]
        int i = task - 3;
        int nb = bx & 7, kb = bx >> 3;
        if (kb >= 16) return;
        int n0 = nb * 32, k0 = kb * 32;
        int tx = t & 31, ty = t >> 5;
        const float* in = a.linW[i];
        u16* out = a.wt2[i];
#pragma unroll
        for (int j = 0; j < 32; j += 8) tile[ty + j][tx] = in[(size_t)(k0 + ty + j) * 256 + n0 + tx];
        __syncthreads();
#pragma unroll
        for (int j = 0; j < 32; j += 8) out[(size_t)(n0 + ty + j) * 512 + k0 + tx] = f2bf(tile[tx][ty + j]);
    } else {                              // wvec fold
        int i = task - 6, k = bx;
        if (k >= a.fin[i]) return;
        volatile float* red4 = &tile[0][0];
        const float* W = a.attW[i];
        float w0 = W[(size_t)k * HE + t];
        float w1 = W[(size_t)k * HE + EMB + t];
        float s0 = block_sum4(w0 * a.asrc[i][t], red4);
        float s1 = block_sum4(w1 * a.asrc[i][EMB + t], red4);
        float d0 = block_sum4(w0 * a.adst[i][t], red4);
        float d1 = block_sum4(w1 * a.adst[i][EMB + t], red4);
        if (t == 0) {
            float* wv = a.wvec + i * 1024 + k * 4;
            wv[0] = s0; wv[1] = s1; wv[2] = d0; wv[3] = d1;
        }
    }
}

// ---------------- edge preprocessing ----------------
__global__ __launch_bounds__(256) void edge_hist(const int* __restrict__ ei, int* __restrict__ deg) {
    int e = blockIdx.x * 256 + threadIdx.x;
    if (e >= ET) return;
    int d = (e < Ee) ? ei[Ee + e] : (e - Ee);
    atomicAdd(&deg[d], 1);
}

__global__ __launch_bounds__(256) void scan_blocks(const int* __restrict__ deg, int* __restrict__ incl,
                                                   int* __restrict__ bsum) {
    __shared__ int buf[256];
    int i = blockIdx.x * 256 + threadIdx.x;
    int v = (i < Nn) ? deg[i] : 0;
    buf[threadIdx.x] = v;
    __syncthreads();
    for (int off = 1; off < 256; off <<= 1) {
        int add = (threadIdx.x >= off) ? buf[threadIdx.x - off] : 0;
        __syncthreads();
        buf[threadIdx.x] += add;
        __syncthreads();
    }
    if (i < Nn) incl[i] = buf[threadIdx.x];
    if (threadIdx.x == 255) bsum[blockIdx.x] = buf[255];
}

// block 0: exclusive scan of NB block sums; block 1: group offsets by binary search
__global__ __launch_bounds__(256) void scan_tops_groups(const int* __restrict__ bsum, int* __restrict__ boff,
                                                        const int* __restrict__ batch, int* __restrict__ gptr) {
    if (blockIdx.x == 0) {
        __shared__ int buf[128];
        int t = threadIdx.x;
        if (t < 128) buf[t] = (t < NB) ? bsum[t] : 0;
        __syncthreads();
        for (int off = 1; off < 128; off <<= 1) {
            int add = 0;
            if (t < 128 && t >= off) add = buf[t - off];
            __syncthreads();
            if (t < 128) buf[t] += add;
            __syncthreads();
        }
        if (t < NB) boff[t] = (t == 0) ? 0 : buf[t - 1];
    } else {
        int g = threadIdx.x;
        if (g > NG) return;
        int lo = 0, hi = Nn;
        while (lo < hi) {
            int mid = (lo + hi) >> 1;
            if (batch[mid] < g) lo = mid + 1; else hi = mid;
        }
        gptr[g] = lo;
    }
}

// rowptr (exclusive) + cursor init in one pass
__global__ __launch_bounds__(256) void scan_add_cursor(const int* __restrict__ incl, const int* __restrict__ boff,
                                                       const int* __restrict__ deg, int* __restrict__ rowptr,
                                                       int* __restrict__ cursor) {
    int i = blockIdx.x * 256 + threadIdx.x;
    if (i < Nn) {
        int inc = incl[i] + boff[blockIdx.x];
        rowptr[i + 1] = inc;
        cursor[i] = inc - deg[i];
    }
    if (i == 0) rowptr[0] = 0;
}

__global__ __launch_bounds__(256) void edge_scatter(const int* __restrict__ ei, int* __restrict__ cursor,
                                                    int* __restrict__ colv) {
    int e = blockIdx.x * 256 + threadIdx.x;
    if (e >= ET) return;
    int s, d;
    if (e < Ee) { s = ei[e]; d = ei[Ee + e]; }
    else        { s = d = e - Ee; }
    int pos = atomicAdd(&cursor[d], 1);
    colv[pos] = s;
}

// ---------------- bf16 MFMA GEMM: C[M,N] = A[M,K] @ Bt[N,K]^T  (m97 structure) ----------------
// lda: A row stride (elements). aoff: added to A row offset when col0 >= 256 (per-head Z select).
#define GL_LDS(gsrc, ldst)                                                               \
    __builtin_amdgcn_global_load_lds(                                                    \
        (const __attribute__((address_space(1))) void*)(unsigned long long)(gsrc),       \
        (__attribute__((address_space(3))) void*)(unsigned)(unsigned long long)(ldst),   \
        16, 0, 0)

__global__ __launch_bounds__(256) void gemm_bf16(const u16* __restrict__ A, int lda, int aoff,
                                                 const u16* __restrict__ Bt, const float* __restrict__ bias,
                                                 u16* __restrict__ Cb, int M, int N, int K, int relu) {
    __shared__ alignas(16) char sA[8192];  // [128 rows][32 k] bf16, row stride 64 B
    __shared__ alignas(16) char sB[8192];  // [128 cols][32 k] bf16
    int tid = threadIdx.x, lane = tid & 63, wid = tid >> 6;
    int l15 = lane & 15, q = lane >> 4;
    int row0 = blockIdx.y * 128, col0 = blockIdx.x * 128;
    int wrow = (wid >> 1) * 64, wcol = (wid & 1) * 64;
    int ao = (col0 >= 256) ? aoff : 0;

    f32x4 acc[4][4];
#pragma unroll
    for (int m = 0; m < 4; m++)
#pragma unroll
        for (int n = 0; n < 4; n++)
#pragma unroll
            for (int e = 0; e < 4; e++) acc[m][n][e] = 0.f;

    for (int k0 = 0; k0 < K; k0 += 32) {
#pragma unroll
        for (int is = 0; is < 2; ++is) {
            int base = is * 4096 + wid * 1024;
            int o = base + lane * 16;
            int row = o >> 6, kb = o & 63;
            int gr = row0 + row; gr = gr < M ? gr : M - 1;  // clamp tail (results discarded)
            const char* src = (const char*)(A + (size_t)gr * lda + ao + k0) + kb;
            GL_LDS(src, sA + base);
        }
#pragma unroll
        for (int is = 0; is < 2; ++is) {
            int base = is * 4096 + wid * 1024;
            int o = base + lane * 16;
            int row = o >> 6, kb = o & 63;
            const char* src = (const char*)(Bt + (size_t)(col0 + row) * K + k0) + kb;
            GL_LDS(src, sB + base);
        }
        __syncthreads();

        bf16x8 af[4], bfr[4];
#pragma unroll
        for (int m = 0; m < 4; m++)
            af[m] = *(const bf16x8*)(sA + ((wrow + m * 16 + l15) << 6) + q * 16);
#pragma unroll
        for (int n = 0; n < 4; n++)
            bfr[n] = *(const bf16x8*)(sB + ((wcol + n * 16 + l15) << 6) + q * 16);
#pragma unroll
        for (int m = 0; m < 4; m++)
#pragma unroll
            for (int n = 0; n < 4; n++)
                acc[m][n] = __builtin_amdgcn_mfma_f32_16x16x32_bf16(af[m], bfr[n], acc[m][n], 0, 0, 0);
        __syncthreads();
    }

    // epilogue: D row = (lane>>4)*4 + reg, col = lane&15
#pragma unroll
    for (int m = 0; m < 4; m++) {
        int rbase = row0 + wrow + m * 16 + q * 4;
#pragma unroll
        for (int reg = 0; reg < 4; reg++) {
            int r = rbase + reg;
            if (r >= M) continue;
#pragma unroll
            for (int n = 0; n < 4; n++) {
                int c = col0 + wcol + n * 16 + l15;
                float v = acc[m][n][reg] + (bias ? bias[c] : 0.f);
                if (relu) v = fmaxf(v, 0.f);
                Cb[(size_t)r * N + c] = f2bf(v);
            }
        }
    }
}

// ---------------- attention logits: wave per node, al = Xb[n,:] @ wvec ----------------
__global__ __launch_bounds__(256) void compute_al_fused(const u16* __restrict__ Xb, const float* __restrict__ wvec,
                                                        float* __restrict__ alsrc, float* __restrict__ aldst,
                                                        int fin) {
    int n = blockIdx.x * 4 + (threadIdx.x >> 6);
    int lane = threadIdx.x & 63;
    float s0 = 0.f, s1 = 0.f, d0 = 0.f, d1 = 0.f;
    for (int j = lane; j < fin; j += 64) {
        float x = bf2f(Xb[(size_t)n * fin + j]);
        float4 w = *(const float4*)(wvec + j * 4);
        s0 += x * w.x; s1 += x * w.y; d0 += x * w.z; d1 += x * w.w;
    }
#pragma unroll
    for (int off = 32; off > 0; off >>= 1) {
        s0 += __shfl_xor(s0, off, 64); s1 += __shfl_xor(s1, off, 64);
        d0 += __shfl_xor(d0, off, 64); d1 += __shfl_xor(d1, off, 64);
    }
    if (lane == 0) {
        alsrc[n * 2 + 0] = s0; alsrc[n * 2 + 1] = s1;
        aldst[n * 2 + 0] = d0; aldst[n * 2 + 1] = d1;
    }
}

__device__ __forceinline__ float lrelu(float x) { return x >= 0.f ? x : SLOPE * x; }

// ---------------- aggregate-then-transform: Z_h[d] = sum_s alpha_h(s,d) X[s] ----------------
// Wave per dst (4/block), edge-unroll 4. Zb row layout: [head0 FIN][head1 FIN].
template <int FIN>
__global__ __launch_bounds__(256) void attn_agg_x(const u16* __restrict__ Xb,
                                                  const float* __restrict__ alsrc,
                                                  const float* __restrict__ aldst,
                                                  const int* __restrict__ row_ptr,
                                                  const int* __restrict__ colv,
                                                  u16* __restrict__ Zb) {
    constexpr int FPL = FIN / 64;
    int d = blockIdx.x * 4 + (threadIdx.x >> 6);
    int lane = threadIdx.x & 63;
    float ad0 = aldst[d * 2 + 0], ad1 = aldst[d * 2 + 1];
    int beg = row_ptr[d], end = row_ptr[d + 1];
    float S0 = 0.f, S1 = 0.f;
    float a0[FPL] = {}, a1[FPL] = {};

    int k = beg;
    for (; k + 3 < end; k += 4) {
        int ss[4];
        float e0[4], e1[4];
        u16 vv[4][FPL];
#pragma unroll
        for (int u = 0; u < 4; u++) ss[u] = colv[k + u];
#pragma unroll
        for (int u = 0; u < 4; u++) {
            float2 l = *(const float2*)(alsrc + ss[u] * 2);
            e0[u] = __expf(lrelu(l.x + ad0));
            e1[u] = __expf(lrelu(l.y + ad1));
            if constexpr (FPL == 4)
                *(ushort4*)vv[u] = *(const ushort4*)(Xb + (size_t)ss[u] * FIN + lane * 4);
            else
                *(ushort2*)vv[u] = *(const ushort2*)(Xb + (size_t)ss[u] * FIN + lane * 2);
        }
#pragma unroll
        for (int u = 0; u < 4; u++) {
            S0 += e0[u]; S1 += e1[u];
#pragma unroll
            for (int j = 0; j < FPL; j++) {
                float x = bf2f(vv[u][j]);
                a0[j] += e0[u] * x;
                a1[j] += e1[u] * x;
            }
        }
    }
    for (; k < end; ++k) {
        int s0 = colv[k];
        float2 l0 = *(const float2*)(alsrc + s0 * 2);
        float e00 = __expf(lrelu(l0.x + ad0)), e01 = __expf(lrelu(l0.y + ad1));
        u16 v0[FPL];
        if constexpr (FPL == 4) *(ushort4*)v0 = *(const ushort4*)(Xb + (size_t)s0 * FIN + lane * 4);
        else                    *(ushort2*)v0 = *(const ushort2*)(Xb + (size_t)s0 * FIN + lane * 2);
        S0 += e00; S1 += e01;
#pragma unroll
        for (int j = 0; j < FPL; j++) {
            float x0 = bf2f(v0[j]);
            a0[j] += e00 * x0;
            a1[j] += e01 * x0;
        }
    }

    float r0 = 1.f / S0, r1 = 1.f / S1;
    u16 o0[FPL], o1[FPL];
#pragma unroll
    for (int j = 0; j < FPL; j++) { o0[j] = f2bf(a0[j] * r0); o1[j] = f2bf(a1[j] * r1); }
    u16* q = Zb + (size_t)d * (2 * FIN);
    if constexpr (FPL == 4) {
        *(ushort4*)(q + lane * 4)       = *(ushort4*)o0;
        *(ushort4*)(q + FIN + lane * 4) = *(ushort4*)o1;
    } else {
        *(ushort2*)(q + lane * 2)       = *(ushort2*)o0;
        *(ushort2*)(q + FIN + lane * 2) = *(ushort2*)o1;
    }
}

// ---------------- pooling: single dispatch per layer, atomic merge ----------------
// pmax: this layer's [128][256] max buffer (zero-init). psum: shared [128][256] sum accumulator.
__global__ __launch_bounds__(256) void pool_atomic(const u16* __restrict__ Xb, const int* __restrict__ gptr,
                                                   float* __restrict__ pmax, float* __restrict__ psum) {
    int g = blockIdx.x, sb = blockIdx.y, t = threadIdx.x;
    int beg = gptr[g], end = gptr[g + 1];
    float mx = 0.f, sm = 0.f;  // X is post-relu (>=0)
    for (int n = beg + sb; n < end; n += PS) {
        float v = bf2f(Xb[(size_t)n * EMB + t]);
        mx = fmaxf(mx, v);
        sm += v;
    }
    // values >= 0: float bits monotone as int
    atomicMax((int*)&pmax[g * EMB + t], __float_as_int(mx));
    atomicAdd(&psum[g * EMB + t], sm);
}

// ---------------- fused head: combines pooled reps, then 2-layer MLP ----------------
__global__ __launch_bounds__(512) void head_fused(const float* __restrict__ pmax3, const float* __restrict__ psum,
                                                  const int* __restrict__ gptr,
                                                  const float* __restrict__ l1W, const float* __restrict__ l1b,
                                                  const float* __restrict__ l2W, const float* __restrict__ l2b,
                                                  float* __restrict__ out) {
    __shared__ float row[512];
    __shared__ float gr[512];
    __shared__ float red[8];
    int r = blockIdx.x, t = threadIdx.x;
    if (t < EMB) {
        row[t] = pmax3[r * EMB + t] + pmax3[32768 + r * EMB + t] + pmax3[65536 + r * EMB + t];
    } else {
        int cnt = gptr[r + 1] - gptr[r];
        row[t] = psum[r * EMB + (t - EMB)] / fmaxf((float)cnt, 1.f);
    }
    __syncthreads();
    float acc = 0.f;
#pragma unroll 8
    for (int k = 0; k < 512; k++) acc += row[k] * l1W[(size_t)k * DENSE + t];
    gr[t] = fmaxf(acc + l1b[t], 0.f);
    __syncthreads();
#pragma unroll
    for (int c = 0; c < NCLS; c++) {
        float p = gr[t] * l2W[(size_t)t * NCLS + c];
        p = wave_sum(p);
        if ((t & 63) == 0) red[t >> 6] = p;
        __syncthreads();
        if (t == 0) {
            float s = 0.f;
#pragma unroll
            for (int i = 0; i < 8; i++) s += red[i];
            out[r * NCLS + c] = s + l2b[c];
        }
        __syncthreads();
    }
}

// ---------------- launch ----------------
extern "C" void kernel_launch(void* const* d_in, const int* in_sizes, int n_in,
                              void* d_out, int out_size, void* d_ws, size_t ws_size,
                              hipStream_t stream) {
    const float* x_in  = (const float*)d_in[0];
    const int*   ei    = (const int*)d_in[1];
    const int*   batch = (const int*)d_in[2];
    const float* attW[3] = {(const float*)d_in[3],  (const float*)d_in[9],  (const float*)d_in[15]};
    const float* asrc[3] = {(const float*)d_in[4],  (const float*)d_in[10], (const float*)d_in[16]};
    const float* adst[3] = {(const float*)d_in[5],  (const float*)d_in[11], (const float*)d_in[17]};
    const float* attB[3] = {(const float*)d_in[6],  (const float*)d_in[12], (const float*)d_in[18]};
    const float* linW[3] = {(const float*)d_in[7],  (const float*)d_in[13], (const float*)d_in[19]};
    const float* linB[3] = {(const float*)d_in[8],  (const float*)d_in[14], (const float*)d_in[20]};
    const float* l1W = (const float*)d_in[21];
    const float* l1b = (const float*)d_in[22];
    const float* l2W = (const float*)d_in[23];
    const float* l2b = (const float*)d_in[24];
    float* out = (float*)d_out;

    char* ws = (char*)d_ws;
    size_t off = 0;
    auto alloc = [&](size_t bytes) -> void* {
        void* p = ws + off;
        off += (bytes + 255) & ~(size_t)255;
        return p;
    };
    u16*   Zb     = (u16*)alloc((size_t)Nn * HE * 2);   // aggregated X per head: [Nn][2*fin]
    u16*   Xb     = (u16*)alloc((size_t)Nn * EMB * 2);
    u16*   Yb     = (u16*)alloc((size_t)Nn * HE * 2);
    u16*   wt1[3], *wt2[3];
    for (int i = 0; i < 3; i++) {
        wt1[i] = (u16*)alloc((size_t)512 * 512 * 2);
        wt2[i] = (u16*)alloc((size_t)256 * 512 * 2);
    }
    float* wvec   = (float*)alloc((size_t)3 * 256 * 4 * 4);
    float* alsrc  = (float*)alloc((size_t)Nn * 2 * 4);
    float* aldst  = (float*)alloc((size_t)Nn * 2 * 4);
    int*   deg    = (int*)alloc((size_t)Nn * 4);
    int*   incl   = (int*)alloc((size_t)Nn * 4);
    int*   bsum   = (int*)alloc((size_t)NB * 4);
    int*   boff   = (int*)alloc((size_t)NB * 4);
    int*   rowptr = (int*)alloc((size_t)(Nn + 1) * 4);
    int*   cursor = (int*)alloc((size_t)Nn * 4);
    int*   colv   = (int*)alloc((size_t)ET * 4);
    int*   gptr   = (int*)alloc((size_t)(NG + 1) * 4);
    float* poolbuf = (float*)alloc((size_t)(3 * NG * EMB + NG * EMB) * 4);  // [3][128][256] pmax + [128][256] psum
    float* pmax3  = poolbuf;
    float* psumA  = poolbuf + 3 * NG * EMB;

    // ---- prologue: input conversion (+deg & pool-buffer zero), weight prep ----
    conv_bf16_zero<<<(Nn * 128 / 4 + 255) / 256, 256, 0, stream>>>(x_in, Xb, Nn * 128 / 4, deg, poolbuf);

    PrepArgs pa;
    for (int i = 0; i < 3; i++) {
        pa.attW[i] = attW[i]; pa.linW[i] = linW[i];
        pa.asrc[i] = asrc[i]; pa.adst[i] = adst[i];
        pa.wt1[i] = wt1[i];   pa.wt2[i] = wt2[i];
        pa.fin[i] = (i == 0) ? 128 : EMB;
    }
    pa.wvec = wvec;
    prep_weights<<<dim3(256, 9), 256, 0, stream>>>(pa);

    // ---- edge preprocessing (CSR by dst) ----
    edge_hist<<<(ET + 255) / 256, 256, 0, stream>>>(ei, deg);
    scan_blocks<<<NB, 256, 0, stream>>>(deg, incl, bsum);
    scan_tops_groups<<<2, 256, 0, stream>>>(bsum, boff, batch, gptr);
    scan_add_cursor<<<NB, 256, 0, stream>>>(incl, boff, deg, rowptr, cursor);
    edge_scatter<<<(ET + 255) / 256, 256, 0, stream>>>(ei, cursor, colv);

    // ---- layers: al -> aggregate X -> Z@W1 (+attB, relu) -> Y@W2 (+linB, relu) -> pool ----
    for (int i = 0; i < 3; i++) {
        int fin = (i == 0) ? 128 : EMB;
        compute_al_fused<<<Nn / 4, 256, 0, stream>>>(Xb, wvec + i * 1024, alsrc, aldst, fin);
        if (fin == 128)
            attn_agg_x<128><<<Nn / 4, 256, 0, stream>>>(Xb, alsrc, aldst, rowptr, colv, Zb);
        else
            attn_agg_x<256><<<Nn / 4, 256, 0, stream>>>(Xb, alsrc, aldst, rowptr, colv, Zb);
        gemm_bf16<<<dim3(512 / 128, (Nn + 127) / 128), 256, 0, stream>>>(
            Zb, 2 * fin, fin, wt1[i], attB[i], Yb, Nn, 512, fin, 1);
        gemm_bf16<<<dim3(256 / 128, (Nn + 127) / 128), 256, 0, stream>>>(
            Yb, 512, 0, wt2[i], linB[i], Xb, Nn, 256, 512, 1);
        pool_atomic<<<dim3(NG, PS), 256, 0, stream>>>(Xb, gptr, pmax3 + i * NG * EMB, psumA);
    }

    // ---- head ----
    head_fused<<<NG, 512, 0, stream>>>(pmax3, psumA, gptr, l1W, l1b, l2W, l2b, out);
}

// Round 14
// 420.049 us; speedup vs baseline: 1.3212x; 1.0449x over previous
//
#include <hip/hip_runtime.h>

#define Nn 20000
#define Ee 240000
#define ET (Ee + Nn)        // 260000 edges incl self-loops
#define EMB 256
#define HE  512             // H * EMB
#define NG  128             // graphs
#define DENSE 512
#define NCLS 10
#define SLOPE 0.2f
#define NB 79               // ceil(Nn/256) scan blocks
#define PS 8                // pool sub-blocks per group

typedef unsigned short u16;
typedef short bf16x8 __attribute__((ext_vector_type(8)));
typedef float f32x4 __attribute__((ext_vector_type(4)));

__device__ __forceinline__ u16 f2bf(float f) {
    unsigned u = __float_as_uint(f);
    unsigned r = (u + 0x7fffu + ((u >> 16) & 1u)) >> 16;
    return (u16)r;
}
__device__ __forceinline__ float bf2f(u16 u) {
    return __uint_as_float(((unsigned)u) << 16);
}

// ---------------- reduction helpers ----------------
__device__ __forceinline__ float wave_sum(float v) {
#pragma unroll
    for (int off = 32; off > 0; off >>= 1) v += __shfl_down(v, off, 64);
    return v;
}
__device__ __forceinline__ float block_sum4(float v, volatile float* red4) {
    v = wave_sum(v);
    if ((threadIdx.x & 63) == 0) red4[threadIdx.x >> 6] = v;
    __syncthreads();
    float r = red4[0] + red4[1] + red4[2] + red4[3];
    __syncthreads();
    return r;
}

// ---------------- fused layer-0 conversion + deg zero + pool-buffer zero ----------------
// poolbuf: [3*128*256 pmax][128*256 psum] = 131072 floats, zeroed by blocks 1000..1511.
__global__ __launch_bounds__(256) void conv_bf16_zero(const float* __restrict__ in, u16* __restrict__ out,
                                                      int n4, int* __restrict__ deg,
                                                      float* __restrict__ poolbuf) {
    if (blockIdx.x < NB) {
        int z = blockIdx.x * 256 + threadIdx.x;
        if (z < Nn) deg[z] = 0;
    }
    if (blockIdx.x >= 1000 && blockIdx.x < 1512) {
        int z = (blockIdx.x - 1000) * 256 + threadIdx.x;   // 0..131071
        poolbuf[z] = 0.f;
    }
    int i = blockIdx.x * 256 + threadIdx.x;
    if (i >= n4) return;
    float4 v = ((const float4*)in)[i];
    ushort4 o;
    o.x = f2bf(v.x); o.y = f2bf(v.y); o.z = f2bf(v.z); o.w = f2bf(v.w);
    ((ushort4*)out)[i] = o;
}

// ---------------- all weight prep in ONE kernel ----------------
struct PrepArgs {
    const float* attW[3]; const float* linW[3];
    const float* asrc[3]; const float* adst[3];
    u16* wt1[3]; u16* wt2[3]; float* wvec;   // wvec: [3][256][4]
    int fin[3];
};

__global__ __launch_bounds__(256) void prep_weights(PrepArgs a) {
    __shared__ float tile[32][33];
    int task = blockIdx.y, bx = blockIdx.x, t = threadIdx.x;
    if (task < 3) {                       // attW[i]: [K=fin][N=512] -> out [512][fin]
        int i = task, K = a.fin[i];
        int nb = bx & 15, kb = bx >> 4;
        if (kb * 32 >= K) return;
        int n0 = nb * 32, k0 = kb * 32;
        int tx = t & 31, ty = t >> 5;
        const float* in = a.attW[i];
        u16* out = a.wt1[i];
#pragma unroll
        for (int j = 0; j < 32; j += 8) tile[ty + j][tx] = in[(size_t)(k0 + ty + j) * 512 + n0 + tx];
        __syncthreads();
#pragma unroll
        for (int j = 0; j < 32; j += 8) out[(size_t)(n0 + ty + j) * K + k0 + tx] = f2bf(tile[tx][ty + j]);
    } else if (task < 6) {                // linW[i]: [512][256] -> out [256][512]
        int i = task - 3;
        int nb = bx & 7, kb = bx >> 3;
        if (kb >= 16) return;
        int n0 = nb * 32, k0 = kb * 32;
        int tx = t & 31, ty = t >> 5;
        const float* in = a.linW[i];
        u16* out = a.wt2[i];
#pragma unroll
        for (int j = 0; j < 32; j += 8) tile[ty + j][tx] = in[(size_t)(k0 + ty + j) * 256 + n0 + tx];
        __syncthreads();
#pragma unroll
        for (int j = 0; j < 32; j += 8) out[(size_t)(n0 + ty + j) * 512 + k0 + tx] = f2bf(tile[tx][ty + j]);
    } else {                              // wvec fold
        int i = task - 6, k = bx;
        if (k >= a.fin[i]) return;
        volatile float* red4 = &tile[0][0];
        const float* W = a.attW[i];
        float w0 = W[(size_t)k * HE + t];
        float w1 = W[(size_t)k * HE + EMB + t];
        float s0 = block_sum4(w0 * a.asrc[i][t], red4);
        float s1 = block_sum4(w1 * a.asrc[i][EMB + t], red4);
        float d0 = block_sum4(w0 * a.adst[i][t], red4);
        float d1 = block_sum4(w1 * a.adst[i][EMB + t], red4);
        if (t == 0) {
            float* wv = a.wvec + i * 1024 + k * 4;
            wv[0] = s0; wv[1] = s1; wv[2] = d0; wv[3] = d1;
        }
    }
}

// ---------------- edge preprocessing ----------------
__global__ __launch_bounds__(256) void edge_hist(const int* __restrict__ ei, int* __restrict__ deg) {
    int e = blockIdx.x * 256 + threadIdx.x;
    if (e >= ET) return;
    int d = (e < Ee) ? ei[Ee + e] : (e - Ee);
    atomicAdd(&deg[d], 1);
}

__global__ __launch_bounds__(256) void scan_blocks(const int* __restrict__ deg, int* __restrict__ incl,
                                                   int* __restrict__ bsum) {
    __shared__ int buf[256];
    int i = blockIdx.x * 256 + threadIdx.x;
    int v = (i < Nn) ? deg[i] : 0;
    buf[threadIdx.x] = v;
    __syncthreads();
    for (int off = 1; off < 256; off <<= 1) {
        int add = (threadIdx.x >= off) ? buf[threadIdx.x - off] : 0;
        __syncthreads();
        buf[threadIdx.x] += add;
        __syncthreads();
    }
    if (i < Nn) incl[i] = buf[threadIdx.x];
    if (threadIdx.x == 255) bsum[blockIdx.x] = buf[255];
}

// block 0: exclusive scan of NB block sums; block 1: group offsets by binary search
__global__ __launch_bounds__(256) void scan_tops_groups(const int* __restrict__ bsum, int* __restrict__ boff,
                                                        const int* __restrict__ batch, int* __restrict__ gptr) {
    if (blockIdx.x == 0) {
        __shared__ int buf[128];
        int t = threadIdx.x;
        if (t < 128) buf[t] = (t < NB) ? bsum[t] : 0;
        __syncthreads();
        for (int off = 1; off < 128; off <<= 1) {
            int add = 0;
            if (t < 128 && t >= off) add = buf[t - off];
            __syncthreads();
            if (t < 128) buf[t] += add;
            __syncthreads();
        }
        if (t < NB) boff[t] = (t == 0) ? 0 : buf[t - 1];
    } else {
        int g = threadIdx.x;
        if (g > NG) return;
        int lo = 0, hi = Nn;
        while (lo < hi) {
            int mid = (lo + hi) >> 1;
            if (batch[mid] < g) lo = mid + 1; else hi = mid;
        }
        gptr[g] = lo;
    }
}

// rowptr (exclusive) + cursor init in one pass
__global__ __launch_bounds__(256) void scan_add_cursor(const int* __restrict__ incl, const int* __restrict__ boff,
                                                       const int* __restrict__ deg, int* __restrict__ rowptr,
                                                       int* __restrict__ cursor) {
    int i = blockIdx.x * 256 + threadIdx.x;
    if (i < Nn) {
        int inc = incl[i] + boff[blockIdx.x];
        rowptr[i + 1] = inc;
        cursor[i] = inc - deg[i];
    }
    if (i == 0) rowptr[0] = 0;
}

__global__ __launch_bounds__(256) void edge_scatter(const int* __restrict__ ei, int* __restrict__ cursor,
                                                    int* __restrict__ colv) {
    int e = blockIdx.x * 256 + threadIdx.x;
    if (e >= ET) return;
    int s, d;
    if (e < Ee) { s = ei[e]; d = ei[Ee + e]; }
    else        { s = d = e - Ee; }
    int pos = atomicAdd(&cursor[d], 1);
    colv[pos] = s;
}

// ---------------- bf16 MFMA GEMM: C[M,N] = A[M,K] @ Bt[N,K]^T  (m97 structure) ----------------
// lda: A row stride (elements). aoff: added to A row offset when col0 >= 256 (per-head Z select).
#define GL_LDS(gsrc, ldst)                                                               \
    __builtin_amdgcn_global_load_lds(                                                    \
        (const __attribute__((address_space(1))) void*)(unsigned long long)(gsrc),       \
        (__attribute__((address_space(3))) void*)(unsigned)(unsigned long long)(ldst),   \
        16, 0, 0)

__global__ __launch_bounds__(256) void gemm_bf16(const u16* __restrict__ A, int lda, int aoff,
                                                 const u16* __restrict__ Bt, const float* __restrict__ bias,
                                                 u16* __restrict__ Cb, int M, int N, int K, int relu) {
    __shared__ alignas(16) char sA[8192];  // [128 rows][32 k] bf16, row stride 64 B
    __shared__ alignas(16) char sB[8192];  // [128 cols][32 k] bf16
    int tid = threadIdx.x, lane = tid & 63, wid = tid >> 6;
    int l15 = lane & 15, q = lane >> 4;
    int row0 = blockIdx.y * 128, col0 = blockIdx.x * 128;
    int wrow = (wid >> 1) * 64, wcol = (wid & 1) * 64;
    int ao = (col0 >= 256) ? aoff : 0;

    f32x4 acc[4][4];
#pragma unroll
    for (int m = 0; m < 4; m++)
#pragma unroll
        for (int n = 0; n < 4; n++)
#pragma unroll
            for (int e = 0; e < 4; e++) acc[m][n][e] = 0.f;

    for (int k0 = 0; k0 < K; k0 += 32) {
#pragma unroll
        for (int is = 0; is < 2; ++is) {
            int base = is * 4096 + wid * 1024;
            int o = base + lane * 16;
            int row = o >> 6, kb = o & 63;
            int gr = row0 + row; gr = gr < M ? gr : M - 1;  // clamp tail (results discarded)
            const char* src = (const char*)(A + (size_t)gr * lda + ao + k0) + kb;
            GL_LDS(src, sA + base);
        }
#pragma unroll
        for (int is = 0; is < 2; ++is) {
            int base = is * 4096 + wid * 1024;
            int o = base + lane * 16;
            int row = o >> 6, kb = o & 63;
            const char* src = (const char*)(Bt + (size_t)(col0 + row) * K + k0) + kb;
            GL_LDS(src, sB + base);
        }
        __syncthreads();

        bf16x8 af[4], bfr[4];
#pragma unroll
        for (int m = 0; m < 4; m++)
            af[m] = *(const bf16x8*)(sA + ((wrow + m * 16 + l15) << 6) + q * 16);
#pragma unroll
        for (int n = 0; n < 4; n++)
            bfr[n] = *(const bf16x8*)(sB + ((wcol + n * 16 + l15) << 6) + q * 16);
#pragma unroll
        for (int m = 0; m < 4; m++)
#pragma unroll
            for (int n = 0; n < 4; n++)
                acc[m][n] = __builtin_amdgcn_mfma_f32_16x16x32_bf16(af[m], bfr[n], acc[m][n], 0, 0, 0);
        __syncthreads();
    }

    // epilogue: D row = (lane>>4)*4 + reg, col = lane&15
#pragma unroll
    for (int m = 0; m < 4; m++) {
        int rbase = row0 + wrow + m * 16 + q * 4;
#pragma unroll
        for (int reg = 0; reg < 4; reg++) {
            int r = rbase + reg;
            if (r >= M) continue;
#pragma unroll
            for (int n = 0; n < 4; n++) {
                int c = col0 + wcol + n * 16 + l15;
                float v = acc[m][n][reg] + (bias ? bias[c] : 0.f);
                if (relu) v = fmaxf(v, 0.f);
                Cb[(size_t)r * N + c] = f2bf(v);
            }
        }
    }
}

// ---------------- attention logits: wave per node, al = Xb[n,:] @ wvec ----------------
__global__ __launch_bounds__(256) void compute_al_fused(const u16* __restrict__ Xb, const float* __restrict__ wvec,
                                                        float* __restrict__ alsrc, float* __restrict__ aldst,
                                                        int fin) {
    int n = blockIdx.x * 4 + (threadIdx.x >> 6);
    int lane = threadIdx.x & 63;
    float s0 = 0.f, s1 = 0.f, d0 = 0.f, d1 = 0.f;
    for (int j = lane; j < fin; j += 64) {
        float x = bf2f(Xb[(size_t)n * fin + j]);
        float4 w = *(const float4*)(wvec + j * 4);
        s0 += x * w.x; s1 += x * w.y; d0 += x * w.z; d1 += x * w.w;
    }
#pragma unroll
    for (int off = 32; off > 0; off >>= 1) {
        s0 += __shfl_xor(s0, off, 64); s1 += __shfl_xor(s1, off, 64);
        d0 += __shfl_xor(d0, off, 64); d1 += __shfl_xor(d1, off, 64);
    }
    if (lane == 0) {
        alsrc[n * 2 + 0] = s0; alsrc[n * 2 + 1] = s1;
        aldst[n * 2 + 0] = d0; aldst[n * 2 + 1] = d1;
    }
}

__device__ __forceinline__ float lrelu(float x) { return x >= 0.f ? x : SLOPE * x; }

// ---------------- aggregate-then-transform: Z_h[d] = sum_s alpha_h(s,d) X[s] ----------------
// Wave per dst (4/block), edge-unroll 4. Zb row layout: [head0 FIN][head1 FIN].
template <int FIN>
__global__ __launch_bounds__(256) void attn_agg_x(const u16* __restrict__ Xb,
                                                  const float* __restrict__ alsrc,
                                                  const float* __restrict__ aldst,
                                                  const int* __restrict__ row_ptr,
                                                  const int* __restrict__ colv,
                                                  u16* __restrict__ Zb) {
    constexpr int FPL = FIN / 64;
    int d = blockIdx.x * 4 + (threadIdx.x >> 6);
    int lane = threadIdx.x & 63;
    float ad0 = aldst[d * 2 + 0], ad1 = aldst[d * 2 + 1];
    int beg = row_ptr[d], end = row_ptr[d + 1];
    float S0 = 0.f, S1 = 0.f;
    float a0[FPL] = {}, a1[FPL] = {};

    int k = beg;
    for (; k + 3 < end; k += 4) {
        int ss[4];
        float e0[4], e1[4];
        u16 vv[4][FPL];
#pragma unroll
        for (int u = 0; u < 4; u++) ss[u] = colv[k + u];
#pragma unroll
        for (int u = 0; u < 4; u++) {
            float2 l = *(const float2*)(alsrc + ss[u] * 2);
            e0[u] = __expf(lrelu(l.x + ad0));
            e1[u] = __expf(lrelu(l.y + ad1));
            if constexpr (FPL == 4)
                *(ushort4*)vv[u] = *(const ushort4*)(Xb + (size_t)ss[u] * FIN + lane * 4);
            else
                *(ushort2*)vv[u] = *(const ushort2*)(Xb + (size_t)ss[u] * FIN + lane * 2);
        }
#pragma unroll
        for (int u = 0; u < 4; u++) {
            S0 += e0[u]; S1 += e1[u];
#pragma unroll
            for (int j = 0; j < FPL; j++) {
                float x = bf2f(vv[u][j]);
                a0[j] += e0[u] * x;
                a1[j] += e1[u] * x;
            }
        }
    }
    for (; k < end; ++k) {
        int s0 = colv[k];
        float2 l0 = *(const float2*)(alsrc + s0 * 2);
        float e00 = __expf(lrelu(l0.x + ad0)), e01 = __expf(lrelu(l0.y + ad1));
        u16 v0[FPL];
        if constexpr (FPL == 4) *(ushort4*)v0 = *(const ushort4*)(Xb + (size_t)s0 * FIN + lane * 4);
        else                    *(ushort2*)v0 = *(const ushort2*)(Xb + (size_t)s0 * FIN + lane * 2);
        S0 += e00; S1 += e01;
#pragma unroll
        for (int j = 0; j < FPL; j++) {
            float x0 = bf2f(v0[j]);
            a0[j] += e00 * x0;
            a1[j] += e01 * x0;
        }
    }

    float r0 = 1.f / S0, r1 = 1.f / S1;
    u16 o0[FPL], o1[FPL];
#pragma unroll
    for (int j = 0; j < FPL; j++) { o0[j] = f2bf(a0[j] * r0); o1[j] = f2bf(a1[j] * r1); }
    u16* q = Zb + (size_t)d * (2 * FIN);
    if constexpr (FPL == 4) {
        *(ushort4*)(q + lane * 4)       = *(ushort4*)o0;
        *(ushort4*)(q + FIN + lane * 4) = *(ushort4*)o1;
    } else {
        *(ushort2*)(q + lane * 2)       = *(ushort2*)o0;
        *(ushort2*)(q + FIN + lane * 2) = *(ushort2*)o1;
    }
}

// ---------------- pooling: single dispatch per layer, atomic merge ----------------
__global__ __launch_bounds__(256) void pool_atomic(const u16* __restrict__ Xb, const int* __restrict__ gptr,
                                                   float* __restrict__ pmax, float* __restrict__ psum) {
    int g = blockIdx.x, sb = blockIdx.y, t = threadIdx.x;
    int beg = gptr[g], end = gptr[g + 1];
    float mx = 0.f, sm = 0.f;  // X is post-relu (>=0)
    for (int n = beg + sb; n < end; n += PS) {
        float v = bf2f(Xb[(size_t)n * EMB + t]);
        mx = fmaxf(mx, v);
        sm += v;
    }
    // values >= 0: float bits monotone as int
    atomicMax((int*)&pmax[g * EMB + t], __float_as_int(mx));
    atomicAdd(&psum[g * EMB + t], sm);
}

// ---------------- head stage 1: g1[r][c] = relu(row(r) . l1W[:,c] + b), split-k x4 ----------------
// grid (8 c-chunks, 128 rows), block 256 = 64 cols x 4 k-quarters. Short 128-FMA chains,
// 1024 blocks -> enough outstanding loads to stream cold l1W at full BW.
__global__ __launch_bounds__(256) void head1(const float* __restrict__ pmax3, const float* __restrict__ psum,
                                             const int* __restrict__ gptr,
                                             const float* __restrict__ l1W, const float* __restrict__ l1b,
                                             float* __restrict__ g1) {
    __shared__ float row[512];
    __shared__ float part[256];
    int r = blockIdx.y, t = threadIdx.x;
    for (int j = t; j < 512; j += 256) {
        float v;
        if (j < EMB) {
            v = pmax3[r * EMB + j] + pmax3[32768 + r * EMB + j] + pmax3[65536 + r * EMB + j];
        } else {
            int cnt = gptr[r + 1] - gptr[r];
            v = psum[r * EMB + (j - EMB)] / fmaxf((float)cnt, 1.f);
        }
        row[j] = v;
    }
    __syncthreads();
    int cl = t & 63, kq = t >> 6;
    int c = blockIdx.x * 64 + cl;
    int k0 = kq * 128;
    float acc = 0.f;
#pragma unroll 8
    for (int k = 0; k < 128; k++) acc += row[k0 + k] * l1W[(size_t)(k0 + k) * DENSE + c];
    part[t] = acc;
    __syncthreads();
    if (kq == 0) {
        float v = part[cl] + part[64 + cl] + part[128 + cl] + part[192 + cl];
        g1[(size_t)r * DENSE + c] = fmaxf(v + l1b[c], 0.f);
    }
}

// ---------------- head stage 2: out = g1 @ l2W + b  [128,512]@[512,10] ----------------
__global__ __launch_bounds__(64) void line2_kernel(const float* __restrict__ g1, const float* __restrict__ W,
                                                   const float* __restrict__ b, float* __restrict__ out) {
    int r = blockIdx.x, t = threadIdx.x;
    float acc[NCLS] = {};
    for (int k = t; k < 2 * EMB; k += 64) {
        float gv = g1[r * 512 + k];
#pragma unroll
        for (int c = 0; c < NCLS; c++) acc[c] += gv * W[k * NCLS + c];
    }
#pragma unroll
    for (int c = 0; c < NCLS; c++) {
        float v = acc[c];
#pragma unroll
        for (int off = 32; off > 0; off >>= 1) v += __shfl_down(v, off, 64);
        if (t == 0) out[r * NCLS + c] = v + b[c];
    }
}

// ---------------- launch ----------------
extern "C" void kernel_launch(void* const* d_in, const int* in_sizes, int n_in,
                              void* d_out, int out_size, void* d_ws, size_t ws_size,
                              hipStream_t stream) {
    const float* x_in  = (const float*)d_in[0];
    const int*   ei    = (const int*)d_in[1];
    const int*   batch = (const int*)d_in[2];
    const float* attW[3] = {(const float*)d_in[3],  (const float*)d_in[9],  (const float*)d_in[15]};
    const float* asrc[3] = {(const float*)d_in[4],  (const float*)d_in[10], (const float*)d_in[16]};
    const float* adst[3] = {(const float*)d_in[5],  (const float*)d_in[11], (const float*)d_in[17]};
    const float* attB[3] = {(const float*)d_in[6],  (const float*)d_in[12], (const float*)d_in[18]};
    const float* linW[3] = {(const float*)d_in[7],  (const float*)d_in[13], (const float*)d_in[19]};
    const float* linB[3] = {(const float*)d_in[8],  (const float*)d_in[14], (const float*)d_in[20]};
    const float* l1W = (const float*)d_in[21];
    const float* l1b = (const float*)d_in[22];
    const float* l2W = (const float*)d_in[23];
    const float* l2b = (const float*)d_in[24];
    float* out = (float*)d_out;

    char* ws = (char*)d_ws;
    size_t off = 0;
    auto alloc = [&](size_t bytes) -> void* {
        void* p = ws + off;
        off += (bytes + 255) & ~(size_t)255;
        return p;
    };
    u16*   Zb     = (u16*)alloc((size_t)Nn * HE * 2);   // aggregated X per head: [Nn][2*fin]
    u16*   Xb     = (u16*)alloc((size_t)Nn * EMB * 2);
    u16*   Yb     = (u16*)alloc((size_t)Nn * HE * 2);
    u16*   wt1[3], *wt2[3];
    for (int i = 0; i < 3; i++) {
        wt1[i] = (u16*)alloc((size_t)512 * 512 * 2);
        wt2[i] = (u16*)alloc((size_t)256 * 512 * 2);
    }
    float* wvec   = (float*)alloc((size_t)3 * 256 * 4 * 4);
    float* alsrc  = (float*)alloc((size_t)Nn * 2 * 4);
    float* aldst  = (float*)alloc((size_t)Nn * 2 * 4);
    int*   deg    = (int*)alloc((size_t)Nn * 4);
    int*   incl   = (int*)alloc((size_t)Nn * 4);
    int*   bsum   = (int*)alloc((size_t)NB * 4);
    int*   boff   = (int*)alloc((size_t)NB * 4);
    int*   rowptr = (int*)alloc((size_t)(Nn + 1) * 4);
    int*   cursor = (int*)alloc((size_t)Nn * 4);
    int*   colv   = (int*)alloc((size_t)ET * 4);
    int*   gptr   = (int*)alloc((size_t)(NG + 1) * 4);
    float* poolbuf = (float*)alloc((size_t)(3 * NG * EMB + NG * EMB) * 4);
    float* pmax3  = poolbuf;
    float* psumA  = poolbuf + 3 * NG * EMB;
    float* g1     = (float*)alloc((size_t)NG * DENSE * 4);

    // ---- prologue: input conversion (+deg & pool-buffer zero), weight prep ----
    conv_bf16_zero<<<(Nn * 128 / 4 + 255) / 256, 256, 0, stream>>>(x_in, Xb, Nn * 128 / 4, deg, poolbuf);

    PrepArgs pa;
    for (int i = 0; i < 3; i++) {
        pa.attW[i] = attW[i]; pa.linW[i] = linW[i];
        pa.asrc[i] = asrc[i]; pa.adst[i] = adst[i];
        pa.wt1[i] = wt1[i];   pa.wt2[i] = wt2[i];
        pa.fin[i] = (i == 0) ? 128 : EMB;
    }
    pa.wvec = wvec;
    prep_weights<<<dim3(256, 9), 256, 0, stream>>>(pa);

    // ---- edge preprocessing (CSR by dst) ----
    edge_hist<<<(ET + 255) / 256, 256, 0, stream>>>(ei, deg);
    scan_blocks<<<NB, 256, 0, stream>>>(deg, incl, bsum);
    scan_tops_groups<<<2, 256, 0, stream>>>(bsum, boff, batch, gptr);
    scan_add_cursor<<<NB, 256, 0, stream>>>(incl, boff, deg, rowptr, cursor);
    edge_scatter<<<(ET + 255) / 256, 256, 0, stream>>>(ei, cursor, colv);

    // ---- layers: al -> aggregate X -> Z@W1 (+attB, relu) -> Y@W2 (+linB, relu) -> pool ----
    for (int i = 0; i < 3; i++) {
        int fin = (i == 0) ? 128 : EMB;
        compute_al_fused<<<Nn / 4, 256, 0, stream>>>(Xb, wvec + i * 1024, alsrc, aldst, fin);
        if (fin == 128)
            attn_agg_x<128><<<Nn / 4, 256, 0, stream>>>(Xb, alsrc, aldst, rowptr, colv, Zb);
        else
            attn_agg_x<256><<<Nn / 4, 256, 0, stream>>>(Xb, alsrc, aldst, rowptr, colv, Zb);
        gemm_bf16<<<dim3(512 / 128, (Nn + 127) / 128), 256, 0, stream>>>(
            Zb, 2 * fin, fin, wt1[i], attB[i], Yb, Nn, 512, fin, 1);
        gemm_bf16<<<dim3(256 / 128, (Nn + 127) / 128), 256, 0, stream>>>(
            Yb, 512, 0, wt2[i], linB[i], Xb, Nn, 256, 512, 1);
        pool_atomic<<<dim3(NG, PS), 256, 0, stream>>>(Xb, gptr, pmax3 + i * NG * EMB, psumA);
    }

    // ---- head: split-k stage then tiny final GEMM ----
    head1<<<dim3(8, NG), 256, 0, stream>>>(pmax3, psumA, gptr, l1W, l1b, g1);
    line2_kernel<<<NG, 64, 0, stream>>>(g1, l2W, l2b, out);
}

// Round 16
// 404.411 us; speedup vs baseline: 1.3723x; 1.0387x over previous
//
#include <hip/hip_runtime.h>

#define Nn 20000
#define Ee 240000
#define ET (Ee + Nn)        // 260000 edges incl self-loops
#define EMB 256
#define HE  512             // H * EMB
#define NG  128             // graphs
#define DENSE 512
#define NCLS 10
#define SLOPE 0.2f
#define NB 79               // ceil(Nn/256) scan blocks
#define PS 8                // pool sub-blocks per group

typedef unsigned short u16;
typedef short bf16x8 __attribute__((ext_vector_type(8)));
typedef float f32x4 __attribute__((ext_vector_type(4)));

__device__ __forceinline__ u16 f2bf(float f) {
    unsigned u = __float_as_uint(f);
    unsigned r = (u + 0x7fffu + ((u >> 16) & 1u)) >> 16;
    return (u16)r;
}
__device__ __forceinline__ float bf2f(u16 u) {
    return __uint_as_float(((unsigned)u) << 16);
}

// ---------------- reduction helpers ----------------
__device__ __forceinline__ float wave_sum(float v) {
#pragma unroll
    for (int off = 32; off > 0; off >>= 1) v += __shfl_down(v, off, 64);
    return v;
}
__device__ __forceinline__ float block_sum4(float v, volatile float* red4) {
    v = wave_sum(v);
    if ((threadIdx.x & 63) == 0) red4[threadIdx.x >> 6] = v;
    __syncthreads();
    float r = red4[0] + red4[1] + red4[2] + red4[3];
    __syncthreads();
    return r;
}

// ---------------- fused prologue: y==0 conv+zeroes; y==1..9 weight prep ----------------
struct PrepArgs {
    const float* attW[3]; const float* linW[3];
    const float* asrc[3]; const float* adst[3];
    u16* wt1[3]; u16* wt2[3]; float* wvec;   // wvec: [3][256][4]
    int fin[3];
};

__global__ __launch_bounds__(256) void prologue_all(const float* __restrict__ xin, u16* __restrict__ Xb,
                                                    int n4, int* __restrict__ deg, float* __restrict__ poolbuf,
                                                    PrepArgs a) {
    __shared__ float tile[32][33];
    int t = threadIdx.x, bx = blockIdx.x, y = blockIdx.y;
    if (y == 0) {
        if (bx < NB) {
            int z = bx * 256 + t;
            if (z < Nn) deg[z] = 0;
        }
        if (bx >= 1000 && bx < 1512) {
            int z = (bx - 1000) * 256 + t;   // 0..131071
            poolbuf[z] = 0.f;
        }
        int i = bx * 256 + t;
        if (i >= n4) return;
        float4 v = ((const float4*)xin)[i];
        ushort4 o;
        o.x = f2bf(v.x); o.y = f2bf(v.y); o.z = f2bf(v.z); o.w = f2bf(v.w);
        ((ushort4*)Xb)[i] = o;
        return;
    }
    int task = y - 1;
    if (task < 3) {                       // attW[i]: [K=fin][N=512] -> wt1[i] bf16 [512][fin]
        if (bx >= 256) return;
        int i = task, K = a.fin[i];
        int nb = bx & 15, kb = bx >> 4;
        if (kb * 32 >= K) return;
        int n0 = nb * 32, k0 = kb * 32;
        int tx = t & 31, ty = t >> 5;
        const float* in = a.attW[i];
        u16* out = a.wt1[i];
#pragma unroll
        for (int j = 0; j < 32; j += 8) tile[ty + j][tx] = in[(size_t)(k0 + ty + j) * 512 + n0 + tx];
        __syncthreads();
#pragma unroll
        for (int j = 0; j < 32; j += 8) out[(size_t)(n0 + ty + j) * K + k0 + tx] = f2bf(tile[tx][ty + j]);
    } else if (task < 6) {                // linW[i]: [512][256] -> wt2[i] bf16 [256][512]
        if (bx >= 128) return;
        int i = task - 3;
        int nb = bx & 7, kb = bx >> 3;
        if (kb >= 16) return;
        int n0 = nb * 32, k0 = kb * 32;
        int tx = t & 31, ty = t >> 5;
        const float* in = a.linW[i];
        u16* out = a.wt2[i];
#pragma unroll
        for (int j = 0; j < 32; j += 8) tile[ty + j][tx] = in[(size_t)(k0 + ty + j) * 256 + n0 + tx];
        __syncthreads();
#pragma unroll
        for (int j = 0; j < 32; j += 8) out[(size_t)(n0 + ty + j) * 512 + k0 + tx] = f2bf(tile[tx][ty + j]);
    } else {                              // wvec fold
        int i = task - 6, k = bx;
        if (k >= a.fin[i]) return;
        volatile float* red4 = &tile[0][0];
        const float* W = a.attW[i];
        float w0 = W[(size_t)k * HE + t];
        float w1 = W[(size_t)k * HE + EMB + t];
        float s0 = block_sum4(w0 * a.asrc[i][t], red4);
        float s1 = block_sum4(w1 * a.asrc[i][EMB + t], red4);
        float d0 = block_sum4(w0 * a.adst[i][t], red4);
        float d1 = block_sum4(w1 * a.adst[i][EMB + t], red4);
        if (t == 0) {
            float* wv = a.wvec + i * 1024 + k * 4;
            wv[0] = s0; wv[1] = s1; wv[2] = d0; wv[3] = d1;
        }
    }
}

// ---------------- edge preprocessing ----------------
__global__ __launch_bounds__(256) void edge_hist(const int* __restrict__ ei, int* __restrict__ deg) {
    int e = blockIdx.x * 256 + threadIdx.x;
    if (e >= ET) return;
    int d = (e < Ee) ? ei[Ee + e] : (e - Ee);
    atomicAdd(&deg[d], 1);
}

__global__ __launch_bounds__(256) void scan_blocks(const int* __restrict__ deg, int* __restrict__ incl,
                                                   int* __restrict__ bsum) {
    __shared__ int buf[256];
    int i = blockIdx.x * 256 + threadIdx.x;
    int v = (i < Nn) ? deg[i] : 0;
    buf[threadIdx.x] = v;
    __syncthreads();
    for (int off = 1; off < 256; off <<= 1) {
        int add = (threadIdx.x >= off) ? buf[threadIdx.x - off] : 0;
        __syncthreads();
        buf[threadIdx.x] += add;
        __syncthreads();
    }
    if (i < Nn) incl[i] = buf[threadIdx.x];
    if (threadIdx.x == 255) bsum[blockIdx.x] = buf[255];
}

// block 0: exclusive scan of NB block sums; block 1: group offsets by binary search
__global__ __launch_bounds__(256) void scan_tops_groups(const int* __restrict__ bsum, int* __restrict__ boff,
                                                        const int* __restrict__ batch, int* __restrict__ gptr) {
    if (blockIdx.x == 0) {
        __shared__ int buf[128];
        int t = threadIdx.x;
        if (t < 128) buf[t] = (t < NB) ? bsum[t] : 0;
        __syncthreads();
        for (int off = 1; off < 128; off <<= 1) {
            int add = 0;
            if (t < 128 && t >= off) add = buf[t - off];
            __syncthreads();
            if (t < 128) buf[t] += add;
            __syncthreads();
        }
        if (t < NB) boff[t] = (t == 0) ? 0 : buf[t - 1];
    } else {
        int g = threadIdx.x;
        if (g > NG) return;
        int lo = 0, hi = Nn;
        while (lo < hi) {
            int mid = (lo + hi) >> 1;
            if (batch[mid] < g) lo = mid + 1; else hi = mid;
        }
        gptr[g] = lo;
    }
}

// rowptr (exclusive) + cursor init in one pass
__global__ __launch_bounds__(256) void scan_add_cursor(const int* __restrict__ incl, const int* __restrict__ boff,
                                                       const int* __restrict__ deg, int* __restrict__ rowptr,
                                                       int* __restrict__ cursor) {
    int i = blockIdx.x * 256 + threadIdx.x;
    if (i < Nn) {
        int inc = incl[i] + boff[blockIdx.x];
        rowptr[i + 1] = inc;
        cursor[i] = inc - deg[i];
    }
    if (i == 0) rowptr[0] = 0;
}

__global__ __launch_bounds__(256) void edge_scatter(const int* __restrict__ ei, int* __restrict__ cursor,
                                                    int* __restrict__ colv) {
    int e = blockIdx.x * 256 + threadIdx.x;
    if (e >= ET) return;
    int s, d;
    if (e < Ee) { s = ei[e]; d = ei[Ee + e]; }
    else        { s = d = e - Ee; }
    int pos = atomicAdd(&cursor[d], 1);
    colv[pos] = s;
}

// ---------------- bf16 MFMA GEMM, BK=64: C[M,N] = A[M,K] @ Bt[N,K]^T ----------------
// LDS: two 8KB half-tiles per operand ([ks][128 rows][64B], 64B row stride as proven).
// lda: A row stride (elements). aoff: added to A row offset when col0 >= 256 (per-head Z select).
#define GL_LDS(gsrc, ldst)                                                               \
    __builtin_amdgcn_global_load_lds(                                                    \
        (const __attribute__((address_space(1))) void*)(unsigned long long)(gsrc),       \
        (__attribute__((address_space(3))) void*)(unsigned)(unsigned long long)(ldst),   \
        16, 0, 0)

__global__ __launch_bounds__(256) void gemm_bf16(const u16* __restrict__ A, int lda, int aoff,
                                                 const u16* __restrict__ Bt, const float* __restrict__ bias,
                                                 u16* __restrict__ Cb, int M, int N, int K, int relu) {
    __shared__ alignas(16) char sA[16384];  // [2][128][64B]
    __shared__ alignas(16) char sB[16384];
    int tid = threadIdx.x, lane = tid & 63, wid = tid >> 6;
    int l15 = lane & 15, q = lane >> 4;
    int row0 = blockIdx.y * 128, col0 = blockIdx.x * 128;
    int wrow = (wid >> 1) * 64, wcol = (wid & 1) * 64;
    int ao = (col0 >= 256) ? aoff : 0;

    f32x4 acc[4][4];
#pragma unroll
    for (int m = 0; m < 4; m++)
#pragma unroll
        for (int n = 0; n < 4; n++)
#pragma unroll
            for (int e = 0; e < 4; e++) acc[m][n][e] = 0.f;

    for (int k0 = 0; k0 < K; k0 += 64) {
#pragma unroll
        for (int is = 0; is < 4; ++is) {
            int base = is * 4096 + wid * 1024;
            int o = base + lane * 16;
            int row = (o >> 6) & 127, ks = o >> 13, kb = o & 63;
            int gr = row0 + row; gr = gr < M ? gr : M - 1;  // clamp tail (results discarded)
            const char* src = (const char*)(A + (size_t)gr * lda + ao + k0) + ks * 64 + kb;
            GL_LDS(src, sA + base);
        }
#pragma unroll
        for (int is = 0; is < 4; ++is) {
            int base = is * 4096 + wid * 1024;
            int o = base + lane * 16;
            int row = (o >> 6) & 127, ks = o >> 13, kb = o & 63;
            const char* src = (const char*)(Bt + (size_t)(col0 + row) * K + k0) + ks * 64 + kb;
            GL_LDS(src, sB + base);
        }
        __syncthreads();

#pragma unroll
        for (int ks = 0; ks < 2; ks++) {
            bf16x8 af[4], bfr[4];
#pragma unroll
            for (int m = 0; m < 4; m++)
                af[m] = *(const bf16x8*)(sA + ks * 8192 + ((wrow + m * 16 + l15) << 6) + q * 16);
#pragma unroll
            for (int n = 0; n < 4; n++)
                bfr[n] = *(const bf16x8*)(sB + ks * 8192 + ((wcol + n * 16 + l15) << 6) + q * 16);
#pragma unroll
            for (int m = 0; m < 4; m++)
#pragma unroll
                for (int n = 0; n < 4; n++)
                    acc[m][n] = __builtin_amdgcn_mfma_f32_16x16x32_bf16(af[m], bfr[n], acc[m][n], 0, 0, 0);
        }
        __syncthreads();
    }

    // epilogue: D row = (lane>>4)*4 + reg, col = lane&15
#pragma unroll
    for (int m = 0; m < 4; m++) {
        int rbase = row0 + wrow + m * 16 + q * 4;
#pragma unroll
        for (int reg = 0; reg < 4; reg++) {
            int r = rbase + reg;
            if (r >= M) continue;
#pragma unroll
            for (int n = 0; n < 4; n++) {
                int c = col0 + wcol + n * 16 + l15;
                float v = acc[m][n][reg] + (bias ? bias[c] : 0.f);
                if (relu) v = fmaxf(v, 0.f);
                Cb[(size_t)r * N + c] = f2bf(v);
            }
        }
    }
}

// ---------------- attention logits (layer 0 only): wave per node, al = Xb[n,:] @ wvec ----------------
__global__ __launch_bounds__(256) void compute_al_fused(const u16* __restrict__ Xb, const float* __restrict__ wvec,
                                                        float* __restrict__ alsrc, float* __restrict__ aldst,
                                                        int fin) {
    int n = blockIdx.x * 4 + (threadIdx.x >> 6);
    int lane = threadIdx.x & 63;
    float s0 = 0.f, s1 = 0.f, d0 = 0.f, d1 = 0.f;
    for (int j = lane; j < fin; j += 64) {
        float x = bf2f(Xb[(size_t)n * fin + j]);
        float4 w = *(const float4*)(wvec + j * 4);
        s0 += x * w.x; s1 += x * w.y; d0 += x * w.z; d1 += x * w.w;
    }
#pragma unroll
    for (int off = 32; off > 0; off >>= 1) {
        s0 += __shfl_xor(s0, off, 64); s1 += __shfl_xor(s1, off, 64);
        d0 += __shfl_xor(d0, off, 64); d1 += __shfl_xor(d1, off, 64);
    }
    if (lane == 0) {
        alsrc[n * 2 + 0] = s0; alsrc[n * 2 + 1] = s1;
        aldst[n * 2 + 0] = d0; aldst[n * 2 + 1] = d1;
    }
}

__device__ __forceinline__ float lrelu(float x) { return x >= 0.f ? x : SLOPE * x; }

// ---------------- aggregate-then-transform: Z_h[d] = sum_s alpha_h(s,d) X[s] ----------------
// Wave per dst (4/block), edge-unroll 4. Zb row layout: [head0 FIN][head1 FIN].
template <int FIN>
__global__ __launch_bounds__(256) void attn_agg_x(const u16* __restrict__ Xb,
                                                  const float* __restrict__ alsrc,
                                                  const float* __restrict__ aldst,
                                                  const int* __restrict__ row_ptr,
                                                  const int* __restrict__ colv,
                                                  u16* __restrict__ Zb) {
    constexpr int FPL = FIN / 64;
    int d = blockIdx.x * 4 + (threadIdx.x >> 6);
    int lane = threadIdx.x & 63;
    float ad0 = aldst[d * 2 + 0], ad1 = aldst[d * 2 + 1];
    int beg = row_ptr[d], end = row_ptr[d + 1];
    float S0 = 0.f, S1 = 0.f;
    float a0[FPL] = {}, a1[FPL] = {};

    int k = beg;
    for (; k + 3 < end; k += 4) {
        int ss[4];
        float e0[4], e1[4];
        u16 vv[4][FPL];
#pragma unroll
        for (int u = 0; u < 4; u++) ss[u] = colv[k + u];
#pragma unroll
        for (int u = 0; u < 4; u++) {
            float2 l = *(const float2*)(alsrc + ss[u] * 2);
            e0[u] = __expf(lrelu(l.x + ad0));
            e1[u] = __expf(lrelu(l.y + ad1));
            if constexpr (FPL == 4)
                *(ushort4*)vv[u] = *(const ushort4*)(Xb + (size_t)ss[u] * FIN + lane * 4);
            else
                *(ushort2*)vv[u] = *(const ushort2*)(Xb + (size_t)ss[u] * FIN + lane * 2);
        }
#pragma unroll
        for (int u = 0; u < 4; u++) {
            S0 += e0[u]; S1 += e1[u];
#pragma unroll
            for (int j = 0; j < FPL; j++) {
                float x = bf2f(vv[u][j]);
                a0[j] += e0[u] * x;
                a1[j] += e1[u] * x;
            }
        }
    }
    for (; k < end; ++k) {
        int s0 = colv[k];
        float2 l0 = *(const float2*)(alsrc + s0 * 2);
        float e00 = __expf(lrelu(l0.x + ad0)), e01 = __expf(lrelu(l0.y + ad1));
        u16 v0[FPL];
        if constexpr (FPL == 4) *(ushort4*)v0 = *(const ushort4*)(Xb + (size_t)s0 * FIN + lane * 4);
        else                    *(ushort2*)v0 = *(const ushort2*)(Xb + (size_t)s0 * FIN + lane * 2);
        S0 += e00; S1 += e01;
#pragma unroll
        for (int j = 0; j < FPL; j++) {
            float x0 = bf2f(v0[j]);
            a0[j] += e00 * x0;
            a1[j] += e01 * x0;
        }
    }

    float r0 = 1.f / S0, r1 = 1.f / S1;
    u16 o0[FPL], o1[FPL];
#pragma unroll
    for (int j = 0; j < FPL; j++) { o0[j] = f2bf(a0[j] * r0); o1[j] = f2bf(a1[j] * r1); }
    u16* q = Zb + (size_t)d * (2 * FIN);
    if constexpr (FPL == 4) {
        *(ushort4*)(q + lane * 4)       = *(ushort4*)o0;
        *(ushort4*)(q + FIN + lane * 4) = *(ushort4*)o1;
    } else {
        *(ushort2*)(q + lane * 2)       = *(ushort2*)o0;
        *(ushort2*)(q + FIN + lane * 2) = *(ushort2*)o1;
    }
}

// ---------------- pool (blocks 0..1023) + next-layer al (blocks 1024..6023) ----------------
// Both read Xb; independent. al part: fin == 256 (layers 1,2).
__global__ __launch_bounds__(256) void pool_al(const u16* __restrict__ Xb, const int* __restrict__ gptr,
                                               float* __restrict__ pmax, float* __restrict__ psum,
                                               const float* __restrict__ wvec,
                                               float* __restrict__ alsrc, float* __restrict__ aldst) {
    int bx = blockIdx.x, t = threadIdx.x;
    if (bx < 1024) {
        int g = bx >> 3, sb = bx & 7;
        int beg = gptr[g], end = gptr[g + 1];
        float mx = 0.f, sm = 0.f;  // X is post-relu (>=0)
        for (int n = beg + sb; n < end; n += PS) {
            float v = bf2f(Xb[(size_t)n * EMB + t]);
            mx = fmaxf(mx, v);
            sm += v;
        }
        atomicMax((int*)&pmax[g * EMB + t], __float_as_int(mx));
        atomicAdd(&psum[g * EMB + t], sm);
    } else {
        int n = (bx - 1024) * 4 + (t >> 6);
        int lane = t & 63;
        float s0 = 0.f, s1 = 0.f, d0 = 0.f, d1 = 0.f;
#pragma unroll
        for (int jj = 0; jj < 4; jj++) {
            int j = lane + jj * 64;
            float x = bf2f(Xb[(size_t)n * EMB + j]);
            float4 w = *(const float4*)(wvec + j * 4);
            s0 += x * w.x; s1 += x * w.y; d0 += x * w.z; d1 += x * w.w;
        }
#pragma unroll
        for (int off = 32; off > 0; off >>= 1) {
            s0 += __shfl_xor(s0, off, 64); s1 += __shfl_xor(s1, off, 64);
            d0 += __shfl_xor(d0, off, 64); d1 += __shfl_xor(d1, off, 64);
        }
        if (lane == 0) {
            alsrc[n * 2 + 0] = s0; alsrc[n * 2 + 1] = s1;
            aldst[n * 2 + 0] = d0; aldst[n * 2 + 1] = d1;
        }
    }
}

// ---------------- head stage 1: split-k x4, 1024 blocks ----------------
__global__ __launch_bounds__(256) void head1(const float* __restrict__ pmax3, const float* __restrict__ psum,
                                             const int* __restrict__ gptr,
                                             const float* __restrict__ l1W, const float* __restrict__ l1b,
                                             float* __restrict__ g1) {
    __shared__ float row[512];
    __shared__ float part[256];
    int r = blockIdx.y, t = threadIdx.x;
    for (int j = t; j < 512; j += 256) {
        float v;
        if (j < EMB) {
            v = pmax3[r * EMB + j] + pmax3[32768 + r * EMB + j] + pmax3[65536 + r * EMB + j];
        } else {
            int cnt = gptr[r + 1] - gptr[r];
            v = psum[r * EMB + (j - EMB)] / fmaxf((float)cnt, 1.f);
        }
        row[j] = v;
    }
    __syncthreads();
    int cl = t & 63, kq = t >> 6;
    int c = blockIdx.x * 64 + cl;
    int k0 = kq * 128;
    float acc = 0.f;
#pragma unroll 8
    for (int k = 0; k < 128; k++) acc += row[k0 + k] * l1W[(size_t)(k0 + k) * DENSE + c];
    part[t] = acc;
    __syncthreads();
    if (kq == 0) {
        float v = part[cl] + part[64 + cl] + part[128 + cl] + part[192 + cl];
        g1[(size_t)r * DENSE + c] = fmaxf(v + l1b[c], 0.f);
    }
}

// ---------------- head stage 2: out = g1 @ l2W + b  [128,512]@[512,10] ----------------
__global__ __launch_bounds__(64) void line2_kernel(const float* __restrict__ g1, const float* __restrict__ W,
                                                   const float* __restrict__ b, float* __restrict__ out) {
    int r = blockIdx.x, t = threadIdx.x;
    float acc[NCLS] = {};
    for (int k = t; k < 2 * EMB; k += 64) {
        float gv = g1[r * 512 + k];
#pragma unroll
        for (int c = 0; c < NCLS; c++) acc[c] += gv * W[k * NCLS + c];
    }
#pragma unroll
    for (int c = 0; c < NCLS; c++) {
        float v = acc[c];
#pragma unroll
        for (int off = 32; off > 0; off >>= 1) v += __shfl_down(v, off, 64);
        if (t == 0) out[r * NCLS + c] = v + b[c];
    }
}

// ---------------- launch ----------------
extern "C" void kernel_launch(void* const* d_in, const int* in_sizes, int n_in,
                              void* d_out, int out_size, void* d_ws, size_t ws_size,
                              hipStream_t stream) {
    const float* x_in  = (const float*)d_in[0];
    const int*   ei    = (const int*)d_in[1];
    const int*   batch = (const int*)d_in[2];
    const float* attW[3] = {(const float*)d_in[3],  (const float*)d_in[9],  (const float*)d_in[15]};
    const float* asrc[3] = {(const float*)d_in[4],  (const float*)d_in[10], (const float*)d_in[16]};
    const float* adst[3] = {(const float*)d_in[5],  (const float*)d_in[11], (const float*)d_in[17]};
    const float* attB[3] = {(const float*)d_in[6],  (const float*)d_in[12], (const float*)d_in[18]};
    const float* linW[3] = {(const float*)d_in[7],  (const float*)d_in[13], (const float*)d_in[19]};
    const float* linB[3] = {(const float*)d_in[8],  (const float*)d_in[14], (const float*)d_in[20]};
    const float* l1W = (const float*)d_in[21];
    const float* l1b = (const float*)d_in[22];
    const float* l2W = (const float*)d_in[23];
    const float* l2b = (const float*)d_in[24];
    float* out = (float*)d_out;

    char* ws = (char*)d_ws;
    size_t off = 0;
    auto alloc = [&](size_t bytes) -> void* {
        void* p = ws + off;
        off += (bytes + 255) & ~(size_t)255;
        return p;
    };
    u16*   Zb     = (u16*)alloc((size_t)Nn * HE * 2);   // aggregated X per head: [Nn][2*fin]
    u16*   Xb     = (u16*)alloc((size_t)Nn * EMB * 2);
    u16*   Yb     = (u16*)alloc((size_t)Nn * HE * 2);
    u16*   wt1[3], *wt2[3];
    for (int i = 0; i < 3; i++) {
        wt1[i] = (u16*)alloc((size_t)512 * 512 * 2);
        wt2[i] = (u16*)alloc((size_t)256 * 512 * 2);
    }
    float* wvec   = (float*)alloc((size_t)3 * 256 * 4 * 4);
    float* alsrc  = (float*)alloc((size_t)Nn * 2 * 4);
    float* aldst  = (float*)alloc((size_t)Nn * 2 * 4);
    int*   deg    = (int*)alloc((size_t)Nn * 4);
    int*   incl   = (int*)alloc((size_t)Nn * 4);
    int*   bsum   = (int*)alloc((size_t)NB * 4);
    int*   boff   = (int*)alloc((size_t)NB * 4);
    int*   rowptr = (int*)alloc((size_t)(Nn + 1) * 4);
    int*   cursor = (int*)alloc((size_t)Nn * 4);
    int*   colv   = (int*)alloc((size_t)ET * 4);
    int*   gptr   = (int*)alloc((size_t)(NG + 1) * 4);
    float* poolbuf = (float*)alloc((size_t)(3 * NG * EMB + NG * EMB) * 4);
    float* pmax3  = poolbuf;
    float* psumA  = poolbuf + 3 * NG * EMB;
    float* g1     = (float*)alloc((size_t)NG * DENSE * 4);

    // ---- prologue: conv (+zeroes) and all weight prep in ONE kernel ----
    PrepArgs pa;
    for (int i = 0; i < 3; i++) {
        pa.attW[i] = attW[i]; pa.linW[i] = linW[i];
        pa.asrc[i] = asrc[i]; pa.adst[i] = adst[i];
        pa.wt1[i] = wt1[i];   pa.wt2[i] = wt2[i];
        pa.fin[i] = (i == 0) ? 128 : EMB;
    }
    pa.wvec = wvec;
    prologue_all<<<dim3(2500, 10), 256, 0, stream>>>(x_in, Xb, Nn * 128 / 4, deg, poolbuf, pa);

    // ---- edge preprocessing (CSR by dst) ----
    edge_hist<<<(ET + 255) / 256, 256, 0, stream>>>(ei, deg);
    scan_blocks<<<NB, 256, 0, stream>>>(deg, incl, bsum);
    scan_tops_groups<<<2, 256, 0, stream>>>(bsum, boff, batch, gptr);
    scan_add_cursor<<<NB, 256, 0, stream>>>(incl, boff, deg, rowptr, cursor);
    edge_scatter<<<(ET + 255) / 256, 256, 0, stream>>>(ei, cursor, colv);

    // ---- layer 0 al ----
    compute_al_fused<<<Nn / 4, 256, 0, stream>>>(Xb, wvec, alsrc, aldst, 128);

    // ---- layers: agg -> Z@W1 (+attB, relu) -> Y@W2 (+linB, relu) -> pool (+next al) ----
    for (int i = 0; i < 3; i++) {
        int fin = (i == 0) ? 128 : EMB;
        if (fin == 128)
            attn_agg_x<128><<<Nn / 4, 256, 0, stream>>>(Xb, alsrc, aldst, rowptr, colv, Zb);
        else
            attn_agg_x<256><<<Nn / 4, 256, 0, stream>>>(Xb, alsrc, aldst, rowptr, colv, Zb);
        gemm_bf16<<<dim3(512 / 128, (Nn + 127) / 128), 256, 0, stream>>>(
            Zb, 2 * fin, fin, wt1[i], attB[i], Yb, Nn, 512, fin, 1);
        gemm_bf16<<<dim3(256 / 128, (Nn + 127) / 128), 256, 0, stream>>>(
            Yb, 512, 0, wt2[i], linB[i], Xb, Nn, 256, 512, 1);
        int nblk = (i < 2) ? (1024 + Nn / 4) : 1024;
        pool_al<<<nblk, 256, 0, stream>>>(Xb, gptr, pmax3 + i * NG * EMB, psumA,
                                          wvec + (i + 1) * 1024, alsrc, aldst);
    }

    // ---- head: split-k stage then tiny final GEMM ----
    head1<<<dim3(8, NG), 256, 0, stream>>>(pmax3, psumA, gptr, l1W, l1b, g1);
    line2_kernel<<<NG, 64, 0, stream>>>(g1, l2W, l2b, out);
}